// Round 3
// baseline (410.690 us; speedup 1.0000x reference)
//
#include <hip/hip_runtime.h>

#define NVOX 200000
#define TM 128
#define NBLK ((NVOX + TM - 1) / TM)   // 1563

typedef unsigned short u16;
typedef unsigned int u32;
typedef __bf16 bf16x8 __attribute__((ext_vector_type(8)));
typedef float f32x16 __attribute__((ext_vector_type(16)));

__device__ __forceinline__ float bf2f(u16 h) { return __uint_as_float(((u32)h) << 16); }
__device__ __forceinline__ u16 f2bf(float x) {
  u32 u = __float_as_uint(x);
  u32 r = u + 0x7fffu + ((u >> 16) & 1u);   // round-to-nearest-even
  return (u16)(r >> 16);
}

#define APAD 72   // u16 row stride for bf16 tiles (conflict-free b128 frags)
#define FPAD 68   // f32 row stride for fp32 epilogue bounce (16B-aligned rows)

__device__ __forceinline__ uint4 apply_affine(uint4 v, int cbase,
                                              const float* sc, const float* sh) {
  u16* p = (u16*)&v;
  uint4 r;
  u16* q = (u16*)&r;
#pragma unroll
  for (int j = 0; j < 8; ++j) {
    float x = bf2f(p[j]);
    x = fmaf(x, sc[cbase + j], sh[cbase + j]);
    q[j] = f2bf(x);
  }
  return r;
}

__device__ __forceinline__ uint4 pack8(float4 a, float4 b) {
  uint4 r;
  u16* q = (u16*)&r;
  q[0] = f2bf(a.x); q[1] = f2bf(a.y); q[2] = f2bf(a.z); q[3] = f2bf(a.w);
  q[4] = f2bf(b.x); q[5] = f2bf(b.y); q[6] = f2bf(b.z); q[7] = f2bf(b.w);
  return r;
}

// Gathered-GEMM stage: t[n,o] = leaky( sum_k sum_c in[nbr[n,k],c] * w[k,c,o] )
// wT: [9][cout][cin] bf16. IN_F32: gather source is fp32 (converted to bf16).
// AFFINE (bf16 input only): gathered rows get scl*x+shf; pad rows stay zero.
// MODE 0: store t bf16 -> y, stats into st[0..127]
// MODE 1: stats only
// MODE 2: y (fp32) = affD(t) + affB(prevf fp32)   [in-place safe: prevf may == y]
// MODE 3: store t fp32 -> y, stats into st
template <bool IN_F32, bool AFFINE, int MODE>
__global__ __launch_bounds__(256, 2)
void conv_k(const void* __restrict__ fv, const int* __restrict__ nbr,
            const u16* __restrict__ wT, const float* __restrict__ scl,
            const float* __restrict__ shf, void* yv,
            float* __restrict__ st, const float* prevf,
            const float* __restrict__ affD, const float* __restrict__ affB) {
  static_assert(!(IN_F32 && AFFINE), "affine only on bf16 intermediates");
  __shared__ __align__(16) u16 a_lds[2][TM][APAD];
  __shared__ __align__(16) u16 w_lds[2][64][APAD];
  __shared__ __align__(16) int nbr_lds[TM * 9];   // reused as float[1024] stats scratch
  __shared__ float sc_s[64], sh_s[64];

  const float* ff = (const float*)fv;
  const u16* fb = (const u16*)fv;

  const int tid = threadIdx.x;
  const int base = blockIdx.x * TM;
  const int wv = tid >> 6;        // wave 0..3 -> rows [32wv, 32wv+32)
  const int lane = tid & 63;
  const int lrow = lane & 31;     // m / n within 32-tile
  const int lq = lane >> 5;       // k-half selector
  const int trow = tid >> 3;      // staging: row group 0..31
  const int cp = tid & 7;         // staging: 8-channel chunk

  if constexpr (AFFINE) {
    if (tid < 64) { sc_s[tid] = scl[tid]; sh_s[tid] = shf[tid]; }
  }
  for (int i = tid; i < TM * 9; i += 256) {
    int row = base + i / 9;
    nbr_lds[i] = (row < NVOX) ? nbr[base * 9 + i] : NVOX;
  }
  __syncthreads();

  // stage k=0 into buffer 0
  {
#pragma unroll
    for (int it = 0; it < 4; ++it) {
      int r = it * 32 + trow;
      int id = nbr_lds[r * 9 + 0];
      uint4 v = make_uint4(0u, 0u, 0u, 0u);
      if (id < NVOX) {
        if constexpr (IN_F32) {
          const float* p = ff + (size_t)id * 64 + cp * 8;
          v = pack8(*(const float4*)p, *(const float4*)(p + 4));
        } else {
          v = *(const uint4*)(fb + (size_t)id * 64 + cp * 8);
          if (AFFINE) v = apply_affine(v, cp * 8, sc_s, sh_s);
        }
      }
      *(uint4*)&a_lds[0][r][cp * 8] = v;
    }
#pragma unroll
    for (int i = 0; i < 2; ++i) {
      int e = (tid + i * 256) * 8;
      *(uint4*)&w_lds[0][e >> 6][e & 63] = *(const uint4*)(wT + e);
    }
  }
  __syncthreads();

  f32x16 acc0 = {0.f, 0.f, 0.f, 0.f, 0.f, 0.f, 0.f, 0.f,
                 0.f, 0.f, 0.f, 0.f, 0.f, 0.f, 0.f, 0.f};
  f32x16 acc1 = acc0;

  int buf = 0;
  for (int k = 0; k < 9; ++k) {
    uint4 pa[4];
    float4 qa0[4], qa1[4];
    int ids[4];
    uint4 pw[2];
    const bool pre = (k < 8);
    if (pre) {  // prefetch raw loads before MFMAs so they overlap compute
#pragma unroll
      for (int it = 0; it < 4; ++it) {
        int r = it * 32 + trow;
        int id = nbr_lds[r * 9 + k + 1];
        ids[it] = id;
        if constexpr (IN_F32) {
          qa0[it] = qa1[it] = make_float4(0.f, 0.f, 0.f, 0.f);
          if (id < NVOX) {
            const float* p = ff + (size_t)id * 64 + cp * 8;
            qa0[it] = *(const float4*)p;
            qa1[it] = *(const float4*)(p + 4);
          }
        } else {
          pa[it] = make_uint4(0u, 0u, 0u, 0u);
          if (id < NVOX) pa[it] = *(const uint4*)(fb + (size_t)id * 64 + cp * 8);
        }
      }
      const u16* wsrc = wT + (k + 1) * 4096;
#pragma unroll
      for (int i = 0; i < 2; ++i) pw[i] = *(const uint4*)(wsrc + (tid + i * 256) * 8);
    }
#pragma unroll
    for (int ks = 0; ks < 4; ++ks) {
      bf16x8 af = __builtin_bit_cast(
          bf16x8, *(const uint4*)&a_lds[buf][32 * wv + lrow][ks * 16 + lq * 8]);
      bf16x8 b0 = __builtin_bit_cast(
          bf16x8, *(const uint4*)&w_lds[buf][lrow][ks * 16 + lq * 8]);
      bf16x8 b1 = __builtin_bit_cast(
          bf16x8, *(const uint4*)&w_lds[buf][32 + lrow][ks * 16 + lq * 8]);
      acc0 = __builtin_amdgcn_mfma_f32_32x32x16_bf16(af, b0, acc0, 0, 0, 0);
      acc1 = __builtin_amdgcn_mfma_f32_32x32x16_bf16(af, b1, acc1, 0, 0, 0);
    }
    if (pre) {
      int nb = buf ^ 1;
#pragma unroll
      for (int it = 0; it < 4; ++it) {
        int r = it * 32 + trow;
        uint4 v;
        if constexpr (IN_F32) {
          v = pack8(qa0[it], qa1[it]);
        } else {
          v = pa[it];
          if (AFFINE && ids[it] < NVOX) v = apply_affine(v, cp * 8, sc_s, sh_s);
        }
        *(uint4*)&a_lds[nb][r][cp * 8] = v;
      }
#pragma unroll
      for (int i = 0; i < 2; ++i) {
        int e = (tid + i * 256) * 8;
        *(uint4*)&w_lds[nb][e >> 6][e & 63] = pw[i];
      }
    }
    __syncthreads();
    buf ^= 1;
  }

  // Epilogue. C/D (32x32): col = lane&31, row = (reg&3) + 8*(reg>>2) + 4*(lane>>5)
  float* stp = (float*)nbr_lds;   // dead after k-loop; 4608B >= 4096B needed
  float* flds = (float*)a_lds;    // fp32 bounce, stride FPAD; 128*68*4 <= 36864B
#pragma unroll
  for (int ct = 0; ct < 2; ++ct) {
    f32x16 a = ct ? acc1 : acc0;
    float s = 0.f, q = 0.f;
    const int c = 32 * ct + lrow;
#pragma unroll
    for (int r = 0; r < 16; ++r) {
      float v = a[r];
      v = v > 0.f ? v : 0.01f * v;
      s += v;
      q += v * v;
      int rowD = (r & 3) + 8 * (r >> 2) + 4 * lq;
      if constexpr (MODE == 0) a_lds[0][32 * wv + rowD][c] = f2bf(v);
      if constexpr (MODE == 3) flds[(32 * wv + rowD) * FPAD + c] = v;
      if constexpr (MODE == 2)
        flds[(32 * wv + rowD) * FPAD + c] = fmaf(v, affD[c], affD[64 + c]);
    }
    if constexpr (MODE != 2) {
      // rows >= NVOX gather only pad -> t==0 -> contribute 0; no guard needed
      stp[(wv * 2 + lq) * 64 + c] = s;
      stp[512 + (wv * 2 + lq) * 64 + c] = q;
    }
  }
  __syncthreads();

  if constexpr (MODE == 0) {
    u16* y = (u16*)yv;
#pragma unroll
    for (int it = 0; it < 4; ++it) {
      int r = it * 32 + trow;
      int row = base + r;
      if (row < NVOX)
        *(uint4*)(y + (size_t)row * 64 + cp * 8) = *(const uint4*)&a_lds[0][r][cp * 8];
    }
  }
  if constexpr (MODE == 3) {
    float* y = (float*)yv;
#pragma unroll
    for (int it = 0; it < 4; ++it) {
      int r = it * 32 + trow;
      int row = base + r;
      if (row < NVOX) {
        *(float4*)(y + (size_t)row * 64 + cp * 8) = *(const float4*)&flds[r * FPAD + cp * 8];
        *(float4*)(y + (size_t)row * 64 + cp * 8 + 4) =
            *(const float4*)&flds[r * FPAD + cp * 8 + 4];
      }
    }
  }
  if constexpr (MODE == 2) {
    float* y = (float*)yv;
#pragma unroll
    for (int it = 0; it < 4; ++it) {
      int r = it * 32 + trow;
      int row = base + r;
      if (row < NVOX) {
        float t[8], p[8];
        *(float4*)&t[0] = *(const float4*)&flds[r * FPAD + cp * 8];
        *(float4*)&t[4] = *(const float4*)&flds[r * FPAD + cp * 8 + 4];
        *(float4*)&p[0] = *(const float4*)(prevf + (size_t)row * 64 + cp * 8);
        *(float4*)&p[4] = *(const float4*)(prevf + (size_t)row * 64 + cp * 8 + 4);
        float o[8];
#pragma unroll
        for (int j = 0; j < 8; ++j) {
          int c = cp * 8 + j;
          o[j] = t[j] + fmaf(p[j], affB[c], affB[64 + c]);
        }
        *(float4*)(y + (size_t)row * 64 + cp * 8) = *(const float4*)&o[0];
        *(float4*)(y + (size_t)row * 64 + cp * 8 + 4) = *(const float4*)&o[4];
      }
    }
  }
  if constexpr (MODE != 2) {
    if (tid < 128) {
      int c = tid & 63;
      int which = tid >> 6;             // 0: sum, 1: sumsq
      const float* pb = stp + which * 512;
      float v = 0.f;
#pragma unroll
      for (int g8 = 0; g8 < 8; ++g8) v += pb[g8 * 64 + c];
      atomicAdd(&st[which * 64 + c], v);
    }
  }
}

// st[0..63]=sum, st[64..127]=sumsq -> st[128+c]=scale, st[192+c]=shift
__global__ void finalize_bn(float* __restrict__ st, const float* __restrict__ g,
                            const float* __restrict__ b) {
  int c = threadIdx.x;
  if (c < 64) {
    const float invn = 1.0f / (float)NVOX;
    float mean = st[c] * invn;
    float var = st[64 + c] * invn - mean * mean;
    float rstd = rsqrtf(var + 1e-5f);
    float sc = g[c] * rstd;
    st[128 + c] = sc;
    st[192 + c] = b[c] - mean * sc;
  }
}

__global__ void zero_stats(float* p) {
  int i = blockIdx.x * 256 + threadIdx.x;
  if (i < 1024) p[i] = 0.f;
}

// w fp32 [9][cin][cout] -> wT bf16 [9][cout][cin], 4 arrays
__global__ void transpose_w(const float* a0, const float* a1, const float* a2,
                            const float* a3, u16* __restrict__ wT) {
  int arr = blockIdx.x / 9, k = blockIdx.x % 9;
  const float* src = (arr == 0) ? a0 : (arr == 1) ? a1 : (arr == 2) ? a2 : a3;
  const float* s = src + k * 4096;
  u16* d = wT + arr * 9 * 4096 + k * 4096;
  for (int i = threadIdx.x; i < 4096; i += 256) {
    int cin = i >> 6, cout = i & 63;
    d[cout * 64 + cin] = f2bf(s[i]);
  }
}

// io (fp32, in place) = affB(io) + affD(yD bf16)
__global__ void final_add(const u16* __restrict__ yD, float* io,
                          const float* __restrict__ affB, const float* __restrict__ affD) {
  int i8 = (blockIdx.x * 256 + threadIdx.x) * 8;
  if (i8 < NVOX * 64) {
    float a[8];
    *(float4*)&a[0] = *(const float4*)(io + i8);
    *(float4*)&a[4] = *(const float4*)(io + i8 + 4);
    uint4 vd = *(const uint4*)(yD + i8);
    const u16* pd = (const u16*)&vd;
    int cb = i8 & 63;
    float o[8];
#pragma unroll
    for (int j = 0; j < 8; ++j) {
      int c = cb + j;
      o[j] = fmaf(a[j], affB[c], affB[64 + c]) + fmaf(bf2f(pd[j]), affD[c], affD[64 + c]);
    }
    *(float4*)(io + i8) = *(const float4*)&o[0];
    *(float4*)(io + i8 + 4) = *(const float4*)&o[4];
  }
}

extern "C" void kernel_launch(void* const* d_in, const int* in_sizes, int n_in,
                              void* d_out, int out_size, void* d_ws, size_t ws_size,
                              hipStream_t stream) {
  const float* feat = (const float*)d_in[0];
  const float* w1 = (const float*)d_in[1];
  const float* w1_2 = (const float*)d_in[2];
  const float* w2 = (const float*)d_in[3];
  const float* w3 = (const float*)d_in[4];
  const float* g0 = (const float*)d_in[5];
  const float* b0 = (const float*)d_in[6];
  const float* g0_2 = (const float*)d_in[7];
  const float* b0_2 = (const float*)d_in[8];
  const float* g1 = (const float*)d_in[9];
  const float* b1 = (const float*)d_in[10];
  const float* g2 = (const float*)d_in[11];
  const float* b2 = (const float*)d_in[12];
  const int* nbr13 = (const int*)d_in[13];
  const int* nbr31 = (const int*)d_in[14];
  float* out = (float*)d_out;

  char* ws = (char*)d_ws;
  float* st = (float*)ws;                       // 4 stages x 256 floats = 4 KB
  u16* wT = (u16*)(ws + 4096);                  // 4 x 9 x 64 x 64 bf16 = 288 KB
  u16* A = (u16*)(ws + 4096 + 294912);          // [N,64] bf16 = 25.6 MB
  u16* B = A + (size_t)NVOX * 64;               // big plan only
  const size_t need_big = 4096 + 294912 + 2ull * NVOX * 64 * 2;
  const bool big = (ws_size >= need_big);

  float* st0 = st;
  float* st1 = st + 256;
  float* st2 = st + 512;
  float* st3 = st + 768;

  zero_stats<<<4, 256, 0, stream>>>(st);
  transpose_w<<<36, 256, 0, stream>>>(w1, w1_2, w2, w3, wT);
  const u16* wT1 = wT;
  const u16* wT12 = wT + 36864;
  const u16* wT2 = wT + 2 * 36864;
  const u16* wT3 = wT + 3 * 36864;

  // shortcut: conv1(feat)->A bf16; conv1_2(A)->out fp32 (pre-BN)
  conv_k<true, false, 0><<<NBLK, 256, 0, stream>>>(feat, nbr13, wT1, nullptr, nullptr,
                                                   A, st0, nullptr, nullptr, nullptr);
  finalize_bn<<<1, 64, 0, stream>>>(st0, g0, b0);
  conv_k<false, true, 3><<<NBLK, 256, 0, stream>>>(A, nbr31, wT12, st0 + 128, st0 + 192,
                                                   out, st1, nullptr, nullptr, nullptr);
  finalize_bn<<<1, 64, 0, stream>>>(st1, g0_2, b0_2);
  // main: conv2(feat)->A (reuse)
  conv_k<true, false, 0><<<NBLK, 256, 0, stream>>>(feat, nbr31, wT2, nullptr, nullptr,
                                                   A, st2, nullptr, nullptr, nullptr);
  finalize_bn<<<1, 64, 0, stream>>>(st2, g1, b1);

  if (big) {
    // conv3(A)->B bf16 (pre-BN); out = BN1_2(out) + BN3(B)
    conv_k<false, true, 0><<<NBLK, 256, 0, stream>>>(A, nbr13, wT3, st2 + 128, st2 + 192,
                                                     B, st3, nullptr, nullptr, nullptr);
    finalize_bn<<<1, 64, 0, stream>>>(st3, g2, b2);
    final_add<<<6250, 256, 0, stream>>>(B, out, st1 + 128, st3 + 128);
  } else {
    // stats pass then fused recompute: out = BN3(conv3(A)) + BN1_2(out)
    conv_k<false, true, 1><<<NBLK, 256, 0, stream>>>(A, nbr13, wT3, st2 + 128, st2 + 192,
                                                     nullptr, st3, nullptr, nullptr, nullptr);
    finalize_bn<<<1, 64, 0, stream>>>(st3, g2, b2);
    conv_k<false, true, 2><<<NBLK, 256, 0, stream>>>(A, nbr13, wT3, st2 + 128, st2 + 192,
                                                     out, nullptr, out, st3 + 128, st1 + 128);
  }
}

// Round 4
// 377.314 us; speedup vs baseline: 1.0885x; 1.0885x over previous
//
#include <hip/hip_runtime.h>

#define NVOX 200000
#define TM 128
#define NBLK ((NVOX + TM - 1) / TM)   // 1563

typedef unsigned short u16;
typedef unsigned int u32;
typedef __bf16 bf16x8 __attribute__((ext_vector_type(8)));
typedef float f32x16 __attribute__((ext_vector_type(16)));

__device__ __forceinline__ float bf2f(u16 h) { return __uint_as_float(((u32)h) << 16); }
__device__ __forceinline__ u16 f2bf(float x) {
  u32 u = __float_as_uint(x);
  u32 r = u + 0x7fffu + ((u >> 16) & 1u);   // round-to-nearest-even
  return (u16)(r >> 16);
}
// two float4 bit-patterns -> 8 bf16
__device__ __forceinline__ uint4 cvt8(uint4 a, uint4 b) {
  const float* fa = (const float*)&a;
  const float* fb = (const float*)&b;
  uint4 r;
  u16* q = (u16*)&r;
#pragma unroll
  for (int j = 0; j < 4; ++j) { q[j] = f2bf(fa[j]); q[4 + j] = f2bf(fb[j]); }
  return r;
}

// Gathered-GEMM: t[n,o] = leaky( sum_k sum_c in[nbr[n,k],c] * w[k,c,o] )
// wfrag: fragment-major weights [9][4ks][2ct][64lane][8] bf16 (per-lane B frags).
// Gathers go straight to A-fragment registers (A[m=lane&31][k=(lane>>5)*8+j]),
// no A-LDS, no K-loop barriers; depth-9 (bf16) / depth-3 (fp32) prefetch.
// MODE 0: store t bf16 -> y, stats into st[0..127]
// MODE 1: stats only
// MODE 2: y (fp32) = affD(t) + affB(prevf)   [in-place: prevf may == y]
// MODE 3: store t fp32 -> y, stats into st
template <bool IN_F32, int MODE>
__global__ __launch_bounds__(256, 2)
void conv_k(const void* __restrict__ fv, const int* __restrict__ nbr,
            const u16* __restrict__ wfrag, void* yv, float* __restrict__ st,
            const float* prevf, const float* __restrict__ affD,
            const float* __restrict__ affB) {
  __shared__ __align__(16) u16 wl[36864];   // 73,728 B; reused as epilogue bounce
  __shared__ float sred[4][128];            // per-wave channel sums/sumsq

  const int tid = threadIdx.x;
  const int wv = tid >> 6;
  const int lane = tid & 63;
  const int lrow = lane & 31;
  const int lq = lane >> 5;
  const int base = blockIdx.x * TM;

  // neighbor ids (issued first; complete while weights stage)
  const int gr = base + wv * 32 + lrow;
  int ids[9];
#pragma unroll
  for (int j = 0; j < 9; ++j) ids[j] = (gr < NVOX) ? nbr[gr * 9 + j] : NVOX;

  // stage fragment-major weights: global -> LDS (once per block)
  {
    const uint4* src = (const uint4*)wfrag;
    uint4* dst = (uint4*)wl;
#pragma unroll
    for (int i = 0; i < 18; ++i) dst[tid + 256 * i] = src[tid + 256 * i];
  }
  __syncthreads();

  constexpr int DEPTH = IN_F32 ? 3 : 9;
  constexpr int SL = IN_F32 ? 8 : 4;
  uint4 araw[DEPTH][SL];

  auto issue = [&](int j, int s) {
    const int id = ids[j];
    const bool ok = (id < NVOX);
    if constexpr (IN_F32) {
      const float* p = (const float*)fv + (size_t)id * 64 + lq * 8;
#pragma unroll
      for (int ks = 0; ks < 4; ++ks) {
        uint4 v0 = make_uint4(0u, 0u, 0u, 0u), v1 = v0;
        if (ok) { v0 = *(const uint4*)(p + ks * 16); v1 = *(const uint4*)(p + ks * 16 + 4); }
        araw[s][ks * 2] = v0;
        araw[s][ks * 2 + 1] = v1;
      }
    } else {
      const u16* p = (const u16*)fv + (size_t)id * 64 + lq * 8;
#pragma unroll
      for (int ks = 0; ks < 4; ++ks) {
        uint4 v = make_uint4(0u, 0u, 0u, 0u);
        if (ok) v = *(const uint4*)(p + ks * 16);
        araw[s][ks] = v;
      }
    }
  };

#pragma unroll
  for (int j = 0; j < DEPTH; ++j) issue(j, j);

  f32x16 acc0 = {0.f, 0.f, 0.f, 0.f, 0.f, 0.f, 0.f, 0.f,
                 0.f, 0.f, 0.f, 0.f, 0.f, 0.f, 0.f, 0.f};
  f32x16 acc1 = acc0;

#pragma unroll
  for (int j = 0; j < 9; ++j) {
    const int s = j % DEPTH;
    uint4 afr[4];
#pragma unroll
    for (int ks = 0; ks < 4; ++ks) {
      if constexpr (IN_F32) afr[ks] = cvt8(araw[s][ks * 2], araw[s][ks * 2 + 1]);
      else afr[ks] = araw[s][ks];
    }
    if constexpr (DEPTH < 9) {
      if (j + DEPTH < 9) issue(j + DEPTH, s);   // afr copies already taken
    }
    const u16* wb = wl + j * 4096;
#pragma unroll
    for (int ks = 0; ks < 4; ++ks) {
      bf16x8 a = __builtin_bit_cast(bf16x8, afr[ks]);
      bf16x8 b0 = __builtin_bit_cast(bf16x8, *(const uint4*)(wb + (ks * 2) * 512 + lane * 8));
      bf16x8 b1 = __builtin_bit_cast(bf16x8, *(const uint4*)(wb + (ks * 2 + 1) * 512 + lane * 8));
      acc0 = __builtin_amdgcn_mfma_f32_32x32x16_bf16(a, b0, acc0, 0, 0, 0);
      acc1 = __builtin_amdgcn_mfma_f32_32x32x16_bf16(a, b1, acc1, 0, 0, 0);
    }
  }

  // Epilogue. C/D (32x32): col = lane&31, row = (reg&3) + 8*(reg>>2) + 4*(lane>>5)
  const int cc0 = lrow, cc1 = 32 + lrow;
  float aD0 = 0.f, aD1 = 0.f, hD0 = 0.f, hD1 = 0.f;
  if constexpr (MODE == 2) {
    aD0 = affD[cc0]; hD0 = affD[64 + cc0];
    aD1 = affD[cc1]; hD1 = affD[64 + cc1];
  }
  float s0 = 0.f, q0 = 0.f, s1 = 0.f, q1 = 0.f;
  float vout[2][16];
#pragma unroll
  for (int r = 0; r < 16; ++r) {
    float v = acc0[r]; v = v > 0.f ? v : 0.01f * v;
    s0 += v; q0 += v * v; vout[0][r] = v;
    float w = acc1[r]; w = w > 0.f ? w : 0.01f * w;
    s1 += w; q1 += w * w; vout[1][r] = w;
  }
  if constexpr (MODE != 2) {
    // fold lq halves (same channels, different rows); rows>=NVOX contribute 0
    s0 += __shfl_xor(s0, 32); q0 += __shfl_xor(q0, 32);
    s1 += __shfl_xor(s1, 32); q1 += __shfl_xor(q1, 32);
    if (lq == 0) {
      sred[wv][lrow] = s0; sred[wv][32 + lrow] = s1;
      sred[wv][64 + lrow] = q0; sred[wv][96 + lrow] = q1;
    }
  }
  __syncthreads();   // all waves done with wl; sred complete

  if constexpr (MODE == 0) {
    u16* bb = wl;   // [128][72]
#pragma unroll
    for (int r = 0; r < 16; ++r) {
      int rowD = 32 * wv + (r & 3) + 8 * (r >> 2) + 4 * lq;
      bb[rowD * 72 + cc0] = f2bf(vout[0][r]);
      bb[rowD * 72 + cc1] = f2bf(vout[1][r]);
    }
  } else if constexpr (MODE == 2 || MODE == 3) {
    float* fb = (float*)wl;   // [128][68]
#pragma unroll
    for (int r = 0; r < 16; ++r) {
      int rowD = 32 * wv + (r & 3) + 8 * (r >> 2) + 4 * lq;
      float v0 = vout[0][r], v1 = vout[1][r];
      if constexpr (MODE == 2) { v0 = fmaf(v0, aD0, hD0); v1 = fmaf(v1, aD1, hD1); }
      fb[rowD * 68 + cc0] = v0;
      fb[rowD * 68 + cc1] = v1;
    }
  }
  __syncthreads();

  const int trow = tid >> 3, cp = tid & 7;
  if constexpr (MODE == 0) {
    u16* y = (u16*)yv;
#pragma unroll
    for (int it = 0; it < 4; ++it) {
      int r = it * 32 + trow, row = base + r;
      if (row < NVOX)
        *(uint4*)(y + (size_t)row * 64 + cp * 8) = *(const uint4*)(wl + r * 72 + cp * 8);
    }
  }
  if constexpr (MODE == 3) {
    float* y = (float*)yv;
    const float* fb = (const float*)wl;
#pragma unroll
    for (int it = 0; it < 4; ++it) {
      int r = it * 32 + trow, row = base + r;
      if (row < NVOX) {
        *(float4*)(y + (size_t)row * 64 + cp * 8) = *(const float4*)(fb + r * 68 + cp * 8);
        *(float4*)(y + (size_t)row * 64 + cp * 8 + 4) = *(const float4*)(fb + r * 68 + cp * 8 + 4);
      }
    }
  }
  if constexpr (MODE == 2) {
    float* y = (float*)yv;
    const float* fb = (const float*)wl;
#pragma unroll
    for (int it = 0; it < 4; ++it) {
      int r = it * 32 + trow, row = base + r;
      if (row < NVOX) {
        float t[8], p[8], o[8];
        *(float4*)&t[0] = *(const float4*)(fb + r * 68 + cp * 8);
        *(float4*)&t[4] = *(const float4*)(fb + r * 68 + cp * 8 + 4);
        *(float4*)&p[0] = *(const float4*)(prevf + (size_t)row * 64 + cp * 8);
        *(float4*)&p[4] = *(const float4*)(prevf + (size_t)row * 64 + cp * 8 + 4);
#pragma unroll
        for (int j = 0; j < 8; ++j) {
          int c = cp * 8 + j;
          o[j] = t[j] + fmaf(p[j], affB[c], affB[64 + c]);
        }
        *(float4*)(y + (size_t)row * 64 + cp * 8) = *(const float4*)&o[0];
        *(float4*)(y + (size_t)row * 64 + cp * 8 + 4) = *(const float4*)&o[4];
      }
    }
  }
  if constexpr (MODE != 2) {
    if (tid < 128) {
      int which = tid >> 6, c = tid & 63;
      float v = sred[0][which * 64 + c] + sred[1][which * 64 + c] +
                sred[2][which * 64 + c] + sred[3][which * 64 + c];
      atomicAdd(&st[which * 64 + c], v);
    }
  }
}

// st[0..63]=sum, st[64..127]=sumsq -> st[128+c]=scale, st[192+c]=shift
__global__ void finalize_bn(float* __restrict__ st, const float* __restrict__ g,
                            const float* __restrict__ b) {
  int c = threadIdx.x;
  if (c < 64) {
    const float invn = 1.0f / (float)NVOX;
    float mean = st[c] * invn;
    float var = st[64 + c] * invn - mean * mean;
    float rstd = rsqrtf(var + 1e-5f);
    float sc = g[c] * rstd;
    st[128 + c] = sc;
    st[192 + c] = b[c] - mean * sc;
  }
}

__global__ void zero_stats(float* p) {
  int i = blockIdx.x * 256 + threadIdx.x;
  if (i < 1024) p[i] = 0.f;
}

// fp32 w [9][cin][cout] -> fragment-major bf16 [9][ks][ct][lane][8], 4 arrays
__global__ void prep_w(const float* a0, const float* a1, const float* a2,
                       const float* a3, u16* __restrict__ wfrag) {
  int e = blockIdx.x * 256 + threadIdx.x;   // < 4*36864
  int arr = e / 36864, r = e % 36864;
  int frag = r >> 9;            // (koff*4+ks)*2+ct
  int lane = (r >> 3) & 63;
  int j = r & 7;
  int koff = frag >> 3, ks = (frag >> 1) & 3, ct = frag & 1;
  int cin = ks * 16 + (lane >> 5) * 8 + j;
  int cout = ct * 32 + (lane & 31);
  const float* src = (arr == 0) ? a0 : (arr == 1) ? a1 : (arr == 2) ? a2 : a3;
  wfrag[e] = f2bf(src[koff * 4096 + cin * 64 + cout]);
}

__global__ void cvt_bf16(const float* __restrict__ x, u16* __restrict__ y) {
  int i8 = (blockIdx.x * 256 + threadIdx.x) * 8;
  if (i8 < NVOX * 64) {
    uint4 a = *(const uint4*)(x + i8);
    uint4 b = *(const uint4*)(x + i8 + 4);
    *(uint4*)(y + i8) = cvt8(a, b);
  }
}

// a := bf16(scale*a + shift), in place (scale=st+128, shift=st+192)
__global__ void bn_apply(u16* a, const float* __restrict__ st) {
  int i8 = (blockIdx.x * 256 + threadIdx.x) * 8;
  if (i8 < NVOX * 64) {
    uint4 v = *(const uint4*)(a + i8);
    const u16* p = (const u16*)&v;
    uint4 o;
    u16* q = (u16*)&o;
    int cb = i8 & 63;
#pragma unroll
    for (int j = 0; j < 8; ++j)
      q[j] = f2bf(fmaf(bf2f(p[j]), st[128 + cb + j], st[192 + cb + j]));
    *(uint4*)(a + i8) = o;
  }
}

// io (fp32, in place) = affB(io) + affD(yD bf16)
__global__ void final_add(const u16* __restrict__ yD, float* io,
                          const float* __restrict__ affB, const float* __restrict__ affD) {
  int i8 = (blockIdx.x * 256 + threadIdx.x) * 8;
  if (i8 < NVOX * 64) {
    float a[8];
    *(float4*)&a[0] = *(const float4*)(io + i8);
    *(float4*)&a[4] = *(const float4*)(io + i8 + 4);
    uint4 vd = *(const uint4*)(yD + i8);
    const u16* pd = (const u16*)&vd;
    int cb = i8 & 63;
    float o[8];
#pragma unroll
    for (int j = 0; j < 8; ++j) {
      int c = cb + j;
      o[j] = fmaf(a[j], affB[c], affB[64 + c]) + fmaf(bf2f(pd[j]), affD[c], affD[64 + c]);
    }
    *(float4*)(io + i8) = *(const float4*)&o[0];
    *(float4*)(io + i8 + 4) = *(const float4*)&o[4];
  }
}

extern "C" void kernel_launch(void* const* d_in, const int* in_sizes, int n_in,
                              void* d_out, int out_size, void* d_ws, size_t ws_size,
                              hipStream_t stream) {
  const float* feat = (const float*)d_in[0];
  const float* w1 = (const float*)d_in[1];
  const float* w1_2 = (const float*)d_in[2];
  const float* w2 = (const float*)d_in[3];
  const float* w3 = (const float*)d_in[4];
  const float* g0 = (const float*)d_in[5];
  const float* b0 = (const float*)d_in[6];
  const float* g0_2 = (const float*)d_in[7];
  const float* b0_2 = (const float*)d_in[8];
  const float* g1 = (const float*)d_in[9];
  const float* b1 = (const float*)d_in[10];
  const float* g2 = (const float*)d_in[11];
  const float* b2 = (const float*)d_in[12];
  const int* nbr13 = (const int*)d_in[13];
  const int* nbr31 = (const int*)d_in[14];
  float* out = (float*)d_out;

  char* ws = (char*)d_ws;
  float* st = (float*)ws;                     // 4 KB
  u16* wf = (u16*)(ws + 4096);                // 288 KB fragment-major weights
  u16* F = (u16*)(ws + 4096 + 294912);        // [N,64] bf16
  u16* A = F + (size_t)NVOX * 64;             // plan Y only
  const size_t need_y = 4096 + 294912 + 2ull * NVOX * 64 * 2;
  const bool planY = (ws_size >= need_y);

  float* st0 = st;
  float* st1 = st + 256;
  float* st2 = st + 512;
  float* st3 = st + 768;
  const u16* wf1 = wf;
  const u16* wf12 = wf + 36864;
  const u16* wf2 = wf + 2 * 36864;
  const u16* wf3 = wf + 3 * 36864;

  zero_stats<<<4, 256, 0, stream>>>(st);
  prep_w<<<576, 256, 0, stream>>>(w1, w1_2, w2, w3, wf);

  if (planY) {
    cvt_bf16<<<6250, 256, 0, stream>>>(feat, F);
    conv_k<false, 0><<<NBLK, 256, 0, stream>>>(F, nbr13, wf1, A, st0, nullptr, nullptr, nullptr);
    finalize_bn<<<1, 64, 0, stream>>>(st0, g0, b0);
    bn_apply<<<6250, 256, 0, stream>>>(A, st0);
    conv_k<false, 3><<<NBLK, 256, 0, stream>>>(A, nbr31, wf12, out, st1, nullptr, nullptr, nullptr);
    finalize_bn<<<1, 64, 0, stream>>>(st1, g0_2, b0_2);
    conv_k<false, 0><<<NBLK, 256, 0, stream>>>(F, nbr31, wf2, A, st2, nullptr, nullptr, nullptr);
    finalize_bn<<<1, 64, 0, stream>>>(st2, g1, b1);
    bn_apply<<<6250, 256, 0, stream>>>(A, st2);
    conv_k<false, 0><<<NBLK, 256, 0, stream>>>(A, nbr13, wf3, F, st3, nullptr, nullptr, nullptr);
    finalize_bn<<<1, 64, 0, stream>>>(st3, g2, b2);
    final_add<<<6250, 256, 0, stream>>>(F, out, st1 + 128, st3 + 128);
  } else {
    // single-buffer plan: fp32 gathers from feat; conv3 recomputed with fused add
    u16* Az = F;
    conv_k<true, 0><<<NBLK, 256, 0, stream>>>(feat, nbr13, wf1, Az, st0, nullptr, nullptr, nullptr);
    finalize_bn<<<1, 64, 0, stream>>>(st0, g0, b0);
    bn_apply<<<6250, 256, 0, stream>>>(Az, st0);
    conv_k<false, 3><<<NBLK, 256, 0, stream>>>(Az, nbr31, wf12, out, st1, nullptr, nullptr, nullptr);
    finalize_bn<<<1, 64, 0, stream>>>(st1, g0_2, b0_2);
    conv_k<true, 0><<<NBLK, 256, 0, stream>>>(feat, nbr31, wf2, Az, st2, nullptr, nullptr, nullptr);
    finalize_bn<<<1, 64, 0, stream>>>(st2, g1, b1);
    bn_apply<<<6250, 256, 0, stream>>>(Az, st2);
    conv_k<false, 1><<<NBLK, 256, 0, stream>>>(Az, nbr13, wf3, nullptr, st3, nullptr, nullptr, nullptr);
    finalize_bn<<<1, 64, 0, stream>>>(st3, g2, b2);
    conv_k<false, 2><<<NBLK, 256, 0, stream>>>(Az, nbr13, wf3, out, nullptr, out, st3 + 128, st1 + 128);
  }
}

// Round 5
// 375.057 us; speedup vs baseline: 1.0950x; 1.0060x over previous
//
#include <hip/hip_runtime.h>

#define NVOX 200000
#define TM 128
#define NBLK 1563   // ceil(200000/128)

typedef unsigned short u16;
typedef unsigned int u32;
typedef __bf16 bf16x8 __attribute__((ext_vector_type(8)));
typedef float f32x16 __attribute__((ext_vector_type(16)));

__device__ __forceinline__ float bf2f(u16 h) { return __uint_as_float(((u32)h) << 16); }
__device__ __forceinline__ u16 f2bf(float x) {
  u32 u = __float_as_uint(x);
  u32 r = u + 0x7fffu + ((u >> 16) & 1u);   // RNE
  return (u16)(r >> 16);
}
__device__ __forceinline__ uint4 cvt8(uint4 a, uint4 b) {
  const float* fa = (const float*)&a;
  const float* fb = (const float*)&b;
  uint4 r;
  u16* q = (u16*)&r;
#pragma unroll
  for (int j = 0; j < 4; ++j) { q[j] = f2bf(fa[j]); q[4 + j] = f2bf(fb[j]); }
  return r;
}

// ---------------------------------------------------------------------------
// conv_k: gathered-GEMM with ballot-skip of empty k-offsets, register-direct
// A-fragment gathers (A[m=lane&31][k=(lane>>5)*8+j]), B-fragments streamed
// from global (L2-hot, identical across blocks). No weight LDS, no K-loop
// barriers. FOLDED: BN of the input is folded into weights + a 5th K-step
// whose A operand is the per-row existence indicator (exact pad semantics).
// MODE 0: store t bf16 -> y, stats into st[0..127]
// MODE 1: stats only
// MODE 2: y (fp32) = affD(t) + affB(io)   [in-place: io may == y]
// MODE 3: store t fp32 -> y, stats into st
// ---------------------------------------------------------------------------
template <bool IN_F32, bool FOLDED, int MODE>
__global__ __launch_bounds__(256, 4)
void conv_k(const void* __restrict__ fv, const int* __restrict__ nbr,
            const u16* __restrict__ wf, void* yv, float* __restrict__ st,
            float* io, const float* __restrict__ affD,
            const float* __restrict__ affB) {
  __shared__ __align__(16) float fb[128 * 68];   // 34,816 B bounce (u16 alias: [128][72])
  __shared__ float sred[4][128];

  const int tid = threadIdx.x;
  const int wv = tid >> 6;
  const int lane = tid & 63;
  const int lrow = lane & 31;
  const int lq = lane >> 5;
  const int base = blockIdx.x * TM;
  const int gr = base + wv * 32 + lrow;

  int ids[9];
#pragma unroll
  for (int j = 0; j < 9; ++j) ids[j] = (gr < NVOX) ? nbr[gr * 9 + j] : NVOX;

  f32x16 acc0 = {0.f, 0.f, 0.f, 0.f, 0.f, 0.f, 0.f, 0.f,
                 0.f, 0.f, 0.f, 0.f, 0.f, 0.f, 0.f, 0.f};
  f32x16 acc1 = acc0;
  constexpr int KSTRIDE = FOLDED ? 5120 : 4096;   // u16 per k-offset

#pragma unroll
  for (int k = 0; k < 9; ++k) {
    if (k != 4) {                               // center always active
      if (__ballot(ids[k] < NVOX) == 0ull) continue;   // ~42% of waves skip
    }
    const int id = ids[k];
    const bool ok = id < NVOX;
    uint4 af[4];
    if constexpr (IN_F32) {
      const float* p = (const float*)fv + (size_t)id * 64 + lq * 8;
#pragma unroll
      for (int ksi = 0; ksi < 4; ++ksi) {
        uint4 v0 = make_uint4(0u, 0u, 0u, 0u), v1 = v0;
        if (ok) { v0 = *(const uint4*)(p + ksi * 16); v1 = *(const uint4*)(p + ksi * 16 + 4); }
        af[ksi] = cvt8(v0, v1);
      }
    } else {
      const u16* p = (const u16*)fv + (size_t)id * 64 + lq * 8;
#pragma unroll
      for (int ksi = 0; ksi < 4; ++ksi) {
        uint4 v = make_uint4(0u, 0u, 0u, 0u);
        if (ok) v = *(const uint4*)(p + ksi * 16);
        af[ksi] = v;
      }
    }
    const u16* wb = wf + k * KSTRIDE;
#pragma unroll
    for (int ksi = 0; ksi < 4; ++ksi) {
      bf16x8 a = __builtin_bit_cast(bf16x8, af[ksi]);
      bf16x8 b0 = __builtin_bit_cast(bf16x8, *(const uint4*)(wb + (ksi * 2) * 512 + lane * 8));
      bf16x8 b1 = __builtin_bit_cast(bf16x8, *(const uint4*)(wb + (ksi * 2 + 1) * 512 + lane * 8));
      acc0 = __builtin_amdgcn_mfma_f32_32x32x16_bf16(a, b0, acc0, 0, 0, 0);
      acc1 = __builtin_amdgcn_mfma_f32_32x32x16_bf16(a, b1, acc1, 0, 0, 0);
    }
    if constexpr (FOLDED) {   // bias channel: A = 1[exists] at (lq=0, j=0)
      uint4 a4 = make_uint4(0u, 0u, 0u, 0u);
      if (lq == 0 && ok) ((u16*)&a4)[0] = 0x3F80u;   // bf16 1.0
      bf16x8 a = __builtin_bit_cast(bf16x8, a4);
      bf16x8 b0 = __builtin_bit_cast(bf16x8, *(const uint4*)(wb + 8 * 512 + lane * 8));
      bf16x8 b1 = __builtin_bit_cast(bf16x8, *(const uint4*)(wb + 9 * 512 + lane * 8));
      acc0 = __builtin_amdgcn_mfma_f32_32x32x16_bf16(a, b0, acc0, 0, 0, 0);
      acc1 = __builtin_amdgcn_mfma_f32_32x32x16_bf16(a, b1, acc1, 0, 0, 0);
    }
  }

  // Epilogue. C/D (32x32): col = lane&31, row = (reg&3) + 8*(reg>>2) + 4*(lane>>5)
  const int cc0 = lrow, cc1 = 32 + lrow;
  float aD0 = 0.f, aD1 = 0.f, hD0 = 0.f, hD1 = 0.f;
  if constexpr (MODE == 2) {
    aD0 = affD[cc0]; hD0 = affD[64 + cc0];
    aD1 = affD[cc1]; hD1 = affD[64 + cc1];
  }
  float s0 = 0.f, q0 = 0.f, s1 = 0.f, q1 = 0.f;
  float vout[2][16];
#pragma unroll
  for (int r = 0; r < 16; ++r) {
    float v = acc0[r]; v = v > 0.f ? v : 0.01f * v;
    s0 += v; q0 += v * v; vout[0][r] = v;
    float w = acc1[r]; w = w > 0.f ? w : 0.01f * w;
    s1 += w; q1 += w * w; vout[1][r] = w;
  }
  if constexpr (MODE != 2) {   // rows >= NVOX contribute exact 0
    s0 += __shfl_xor(s0, 32); q0 += __shfl_xor(q0, 32);
    s1 += __shfl_xor(s1, 32); q1 += __shfl_xor(q1, 32);
    if (lq == 0) {
      sred[wv][lrow] = s0; sred[wv][32 + lrow] = s1;
      sred[wv][64 + lrow] = q0; sred[wv][96 + lrow] = q1;
    }
  }
  if constexpr (MODE == 0) {
    u16* bb = (u16*)fb;   // [128][72]
#pragma unroll
    for (int r = 0; r < 16; ++r) {
      int rowD = 32 * wv + (r & 3) + 8 * (r >> 2) + 4 * lq;
      bb[rowD * 72 + cc0] = f2bf(vout[0][r]);
      bb[rowD * 72 + cc1] = f2bf(vout[1][r]);
    }
  } else if constexpr (MODE == 2 || MODE == 3) {
#pragma unroll
    for (int r = 0; r < 16; ++r) {
      int rowD = 32 * wv + (r & 3) + 8 * (r >> 2) + 4 * lq;
      float v0 = vout[0][r], v1 = vout[1][r];
      if constexpr (MODE == 2) { v0 = fmaf(v0, aD0, hD0); v1 = fmaf(v1, aD1, hD1); }
      fb[rowD * 68 + cc0] = v0;
      fb[rowD * 68 + cc1] = v1;
    }
  }
  __syncthreads();

  const int trow = tid >> 3, cp = tid & 7;
  if constexpr (MODE == 0) {
    u16* y = (u16*)yv;
    const u16* bb = (const u16*)fb;
#pragma unroll
    for (int it = 0; it < 4; ++it) {
      int r = it * 32 + trow, row = base + r;
      if (row < NVOX)
        *(uint4*)(y + (size_t)row * 64 + cp * 8) = *(const uint4*)(bb + r * 72 + cp * 8);
    }
  }
  if constexpr (MODE == 3) {
    float* y = (float*)yv;
#pragma unroll
    for (int it = 0; it < 4; ++it) {
      int r = it * 32 + trow, row = base + r;
      if (row < NVOX) {
        *(float4*)(y + (size_t)row * 64 + cp * 8) = *(const float4*)(fb + r * 68 + cp * 8);
        *(float4*)(y + (size_t)row * 64 + cp * 8 + 4) = *(const float4*)(fb + r * 68 + cp * 8 + 4);
      }
    }
  }
  if constexpr (MODE == 2) {
    float* y = (float*)yv;
#pragma unroll
    for (int it = 0; it < 4; ++it) {
      int r = it * 32 + trow, row = base + r;
      if (row < NVOX) {
        float t[8], p[8], o[8];
        *(float4*)&t[0] = *(const float4*)(fb + r * 68 + cp * 8);
        *(float4*)&t[4] = *(const float4*)(fb + r * 68 + cp * 8 + 4);
        *(float4*)&p[0] = *(const float4*)(io + (size_t)row * 64 + cp * 8);
        *(float4*)&p[4] = *(const float4*)(io + (size_t)row * 64 + cp * 8 + 4);
#pragma unroll
        for (int j = 0; j < 8; ++j) {
          int c = cp * 8 + j;
          o[j] = t[j] + fmaf(p[j], affB[c], affB[64 + c]);
        }
        *(float4*)(y + (size_t)row * 64 + cp * 8) = *(const float4*)&o[0];
        *(float4*)(y + (size_t)row * 64 + cp * 8 + 4) = *(const float4*)&o[4];
      }
    }
  }
  if constexpr (MODE != 2) {
    if (tid < 128) {
      int which = tid >> 6, c = tid & 63;
      float v = sred[0][which * 64 + c] + sred[1][which * 64 + c] +
                sred[2][which * 64 + c] + sred[3][which * 64 + c];
      atomicAdd(&st[which * 64 + c], v);
    }
  }
}

// prep: feat fp32 -> bf16 (big plan), raw weight fragments (w1, w2), zero stats
__global__ void prep_all(const float* __restrict__ feat, const float* __restrict__ w1,
                         const float* __restrict__ w2, u16* __restrict__ wf,
                         u16* __restrict__ F, float* __restrict__ st, int cvt_blocks) {
  const int bid = blockIdx.x, tid = threadIdx.x;
  if (bid < cvt_blocks) {
    int i8 = (bid * 256 + tid) * 8;
    if (i8 < NVOX * 64) {
      uint4 a = *(const uint4*)(feat + i8);
      uint4 b = *(const uint4*)(feat + i8 + 4);
      *(uint4*)(F + i8) = cvt8(a, b);
    }
    return;
  }
  int rb = bid - cvt_blocks;
  if (rb < 288) {   // raw frags: [slot 0|1][k][ks*2+ct][lane][j], 36864 u16/slot
    int e = rb * 256 + tid;
    int slot = e / 36864, r = e % 36864;
    int k = r >> 12, rr = r & 4095;
    int frag = rr >> 9, lane = (rr >> 3) & 63, j = rr & 7;
    int ks = frag >> 1, ct = frag & 1;
    int cin = ks * 16 + (lane >> 5) * 8 + j;
    int cout = ct * 32 + (lane & 31);
    const float* src = slot ? w2 : w1;
    wf[e] = f2bf(src[k * 4096 + cin * 64 + cout]);
    return;
  }
  for (int i = tid; i < 1024; i += 256) st[i] = 0.f;
}

// fold BN(stp,g,b) into wraw -> folded frag slot (ks=0..3 scaled, ks=4 bias row)
__global__ void wscale(const float* __restrict__ wraw, float* __restrict__ stp,
                       const float* __restrict__ g, const float* __restrict__ b,
                       u16* __restrict__ dst) {
  __shared__ float sc[64], sh[64];
  const int tid = threadIdx.x;
  if (tid < 64) {
    const float invn = 1.0f / (float)NVOX;
    float mean = stp[tid] * invn;
    float var = stp[64 + tid] * invn - mean * mean;
    float s = g[tid] * rsqrtf(var + 1e-5f);
    sc[tid] = s;
    sh[tid] = b[tid] - mean * s;
    if (blockIdx.x == 0) { stp[128 + tid] = s; stp[192 + tid] = sh[tid]; }
  }
  __syncthreads();
  int e = blockIdx.x * 256 + tid;   // [0, 46080)
  int k = e / 5120, r = e % 5120;
  int frag = r >> 9, lane = (r >> 3) & 63, j = r & 7;
  int ks = frag >> 1, ct = frag & 1;
  int cout = ct * 32 + (lane & 31);
  u16 val = 0;
  if (ks < 4) {
    int cin = ks * 16 + (lane >> 5) * 8 + j;
    val = f2bf(sc[cin] * wraw[k * 4096 + cin * 64 + cout]);
  } else if (((lane >> 5) == 0) && j == 0) {
    float acc = 0.f;
    for (int c = 0; c < 64; ++c) acc += sh[c] * wraw[k * 4096 + c * 64 + cout];
    val = f2bf(acc);
  }
  dst[e] = val;
}

__global__ void finalize_bn(float* __restrict__ st, const float* __restrict__ g,
                            const float* __restrict__ b) {
  int c = threadIdx.x;
  if (c < 64) {
    const float invn = 1.0f / (float)NVOX;
    float mean = st[c] * invn;
    float var = st[64 + c] * invn - mean * mean;
    float s = g[c] * rsqrtf(var + 1e-5f);
    st[128 + c] = s;
    st[192 + c] = b[c] - mean * s;
  }
}

// out (fp32, in place) = BN1(out) + BN3(y3 bf16); affines computed in-kernel
__global__ void final_add2(const u16* __restrict__ y3, float* io,
                           const float* __restrict__ st1, const float* __restrict__ g12,
                           const float* __restrict__ b12, const float* __restrict__ st3,
                           const float* __restrict__ g2, const float* __restrict__ b2) {
  __shared__ float a1[64], h1[64], a3[64], h3[64];
  const int tid = threadIdx.x;
  if (tid < 64) {
    const float invn = 1.0f / (float)NVOX;
    float m = st1[tid] * invn, v = st1[64 + tid] * invn - m * m;
    float s = g12[tid] * rsqrtf(v + 1e-5f);
    a1[tid] = s; h1[tid] = b12[tid] - m * s;
    m = st3[tid] * invn; v = st3[64 + tid] * invn - m * m;
    s = g2[tid] * rsqrtf(v + 1e-5f);
    a3[tid] = s; h3[tid] = b2[tid] - m * s;
  }
  __syncthreads();
  int i8 = (blockIdx.x * 256 + tid) * 8;
  if (i8 < NVOX * 64) {
    float a[8];
    *(float4*)&a[0] = *(const float4*)(io + i8);
    *(float4*)&a[4] = *(const float4*)(io + i8 + 4);
    uint4 vd = *(const uint4*)(y3 + i8);
    const u16* pd = (const u16*)&vd;
    int cb = i8 & 63;
    float o[8];
#pragma unroll
    for (int j = 0; j < 8; ++j) {
      int c = cb + j;
      o[j] = fmaf(a[j], a1[c], h1[c]) + fmaf(bf2f(pd[j]), a3[c], h3[c]);
    }
    *(float4*)(io + i8) = *(const float4*)&o[0];
    *(float4*)(io + i8 + 4) = *(const float4*)&o[4];
  }
}

extern "C" void kernel_launch(void* const* d_in, const int* in_sizes, int n_in,
                              void* d_out, int out_size, void* d_ws, size_t ws_size,
                              hipStream_t stream) {
  const float* feat = (const float*)d_in[0];
  const float* w1 = (const float*)d_in[1];
  const float* w1_2 = (const float*)d_in[2];
  const float* w2 = (const float*)d_in[3];
  const float* w3 = (const float*)d_in[4];
  const float* g0 = (const float*)d_in[5];
  const float* b0 = (const float*)d_in[6];
  const float* g0_2 = (const float*)d_in[7];
  const float* b0_2 = (const float*)d_in[8];
  const float* g1 = (const float*)d_in[9];
  const float* b1 = (const float*)d_in[10];
  const float* g2 = (const float*)d_in[11];
  const float* b2 = (const float*)d_in[12];
  const int* nbr13 = (const int*)d_in[13];
  const int* nbr31 = (const int*)d_in[14];
  float* out = (float*)d_out;

  char* ws = (char*)d_ws;
  float* st = (float*)ws;                         // 4 KB
  u16* wf = (u16*)(ws + 4096);                    // 331,776 B of fragments
  u16* s0 = wf;                                   // w1 raw      (36,864 u16)
  u16* s1 = wf + 36864;                           // w2 raw
  u16* s2 = wf + 73728;                           // w1_2 folded (46,080 u16)
  u16* s3 = wf + 119808;                          // w3 folded
  u16* F = (u16*)(ws + 4096 + 331776);            // feat bf16, 25.6 MB
  u16* A = F + (size_t)NVOX * 64;                 // intermediate, 25.6 MB
  const size_t need_big = 4096 + 331776 + 2ull * NVOX * 64 * 2;
  const bool big = (ws_size >= need_big);

  float* st0 = st, *st1 = st + 256, *st2 = st + 512, *st3 = st + 768;

  if (big) {
    prep_all<<<6539, 256, 0, stream>>>(feat, w1, w2, wf, F, st, 6250);
    conv_k<false, false, 0><<<NBLK, 256, 0, stream>>>(F, nbr13, s0, A, st0, nullptr, nullptr, nullptr);
    wscale<<<180, 256, 0, stream>>>(w1_2, st0, g0, b0, s2);
    conv_k<false, true, 3><<<NBLK, 256, 0, stream>>>(A, nbr31, s2, out, st1, nullptr, nullptr, nullptr);
    conv_k<false, false, 0><<<NBLK, 256, 0, stream>>>(F, nbr31, s1, A, st2, nullptr, nullptr, nullptr);
    wscale<<<180, 256, 0, stream>>>(w3, st2, g1, b1, s3);
    conv_k<false, true, 0><<<NBLK, 256, 0, stream>>>(A, nbr13, s3, F, st3, nullptr, nullptr, nullptr);
    final_add2<<<6250, 256, 0, stream>>>(F, out, st1, g0_2, b0_2, st3, g2, b2);
  } else {
    // single-buffer fallback: fp32 gathers from feat; conv3 stats pass + fused recompute
    u16* Az = F;
    prep_all<<<289, 256, 0, stream>>>(feat, w1, w2, wf, nullptr, st, 0);
    conv_k<true, false, 0><<<NBLK, 256, 0, stream>>>(feat, nbr13, s0, Az, st0, nullptr, nullptr, nullptr);
    wscale<<<180, 256, 0, stream>>>(w1_2, st0, g0, b0, s2);
    conv_k<false, true, 3><<<NBLK, 256, 0, stream>>>(Az, nbr31, s2, out, st1, nullptr, nullptr, nullptr);
    finalize_bn<<<1, 64, 0, stream>>>(st1, g0_2, b0_2);
    conv_k<true, false, 0><<<NBLK, 256, 0, stream>>>(feat, nbr31, s1, Az, st2, nullptr, nullptr, nullptr);
    wscale<<<180, 256, 0, stream>>>(w3, st2, g1, b1, s3);
    conv_k<false, true, 1><<<NBLK, 256, 0, stream>>>(Az, nbr13, s3, nullptr, st3, nullptr, nullptr, nullptr);
    finalize_bn<<<1, 64, 0, stream>>>(st3, g2, b2);
    conv_k<false, true, 2><<<NBLK, 256, 0, stream>>>(Az, nbr13, s3, out, nullptr, out, st3 + 128, st1 + 128);
  }
}

// Round 6
// 287.619 us; speedup vs baseline: 1.4279x; 1.3040x over previous
//
#include <hip/hip_runtime.h>

#define NVOX 200000
#define TM 128
#define NBLK 1563   // ceil(200000/128)
#define NREP 32     // stats-accumulator replicas (kills same-address atomic chains)
#define STG 4224    // floats per stage: 32*128 replicas + 64 scale + 64 shift

typedef unsigned short u16;
typedef unsigned int u32;
typedef __bf16 bf16x8 __attribute__((ext_vector_type(8)));
typedef float f32x16 __attribute__((ext_vector_type(16)));

__device__ __forceinline__ float bf2f(u16 h) { return __uint_as_float(((u32)h) << 16); }
__device__ __forceinline__ u16 f2bf(float x) {
  u32 u = __float_as_uint(x);
  u32 r = u + 0x7fffu + ((u >> 16) & 1u);   // RNE
  return (u16)(r >> 16);
}
__device__ __forceinline__ uint4 cvt8(uint4 a, uint4 b) {
  const float* fa = (const float*)&a;
  const float* fb = (const float*)&b;
  uint4 r;
  u16* q = (u16*)&r;
#pragma unroll
  for (int j = 0; j < 4; ++j) { q[j] = f2bf(fa[j]); q[4 + j] = f2bf(fb[j]); }
  return r;
}

// ---------------------------------------------------------------------------
// conv_k: identical K-loop to round 5 (ballot-skip, register-direct A gathers,
// B-fragments from L2). ONLY change: stats go to one of 32 replica slots.
// MODE 0: store t bf16 -> y, stats    MODE 1: stats only
// MODE 2: y (fp32) = affD(t) + affB(io)  [in-place]
// MODE 3: store t fp32 -> y, stats
// ---------------------------------------------------------------------------
template <bool IN_F32, bool FOLDED, int MODE>
__global__ __launch_bounds__(256, 4)
void conv_k(const void* __restrict__ fv, const int* __restrict__ nbr,
            const u16* __restrict__ wf, void* yv, float* __restrict__ st,
            float* io, const float* __restrict__ affD,
            const float* __restrict__ affB) {
  __shared__ __align__(16) float fb[128 * 68];   // bounce (u16 alias: [128][72])
  __shared__ float sred[4][128];

  const int tid = threadIdx.x;
  const int wv = tid >> 6;
  const int lane = tid & 63;
  const int lrow = lane & 31;
  const int lq = lane >> 5;
  const int base = blockIdx.x * TM;
  const int gr = base + wv * 32 + lrow;

  int ids[9];
#pragma unroll
  for (int j = 0; j < 9; ++j) ids[j] = (gr < NVOX) ? nbr[gr * 9 + j] : NVOX;

  f32x16 acc0 = {0.f, 0.f, 0.f, 0.f, 0.f, 0.f, 0.f, 0.f,
                 0.f, 0.f, 0.f, 0.f, 0.f, 0.f, 0.f, 0.f};
  f32x16 acc1 = acc0;
  constexpr int KSTRIDE = FOLDED ? 5120 : 4096;

#pragma unroll
  for (int k = 0; k < 9; ++k) {
    if (k != 4) {
      if (__ballot(ids[k] < NVOX) == 0ull) continue;
    }
    const int id = ids[k];
    const bool ok = id < NVOX;
    uint4 af[4];
    if constexpr (IN_F32) {
      const float* p = (const float*)fv + (size_t)id * 64 + lq * 8;
#pragma unroll
      for (int ksi = 0; ksi < 4; ++ksi) {
        uint4 v0 = make_uint4(0u, 0u, 0u, 0u), v1 = v0;
        if (ok) { v0 = *(const uint4*)(p + ksi * 16); v1 = *(const uint4*)(p + ksi * 16 + 4); }
        af[ksi] = cvt8(v0, v1);
      }
    } else {
      const u16* p = (const u16*)fv + (size_t)id * 64 + lq * 8;
#pragma unroll
      for (int ksi = 0; ksi < 4; ++ksi) {
        uint4 v = make_uint4(0u, 0u, 0u, 0u);
        if (ok) v = *(const uint4*)(p + ksi * 16);
        af[ksi] = v;
      }
    }
    const u16* wb = wf + k * KSTRIDE;
#pragma unroll
    for (int ksi = 0; ksi < 4; ++ksi) {
      bf16x8 a = __builtin_bit_cast(bf16x8, af[ksi]);
      bf16x8 b0 = __builtin_bit_cast(bf16x8, *(const uint4*)(wb + (ksi * 2) * 512 + lane * 8));
      bf16x8 b1 = __builtin_bit_cast(bf16x8, *(const uint4*)(wb + (ksi * 2 + 1) * 512 + lane * 8));
      acc0 = __builtin_amdgcn_mfma_f32_32x32x16_bf16(a, b0, acc0, 0, 0, 0);
      acc1 = __builtin_amdgcn_mfma_f32_32x32x16_bf16(a, b1, acc1, 0, 0, 0);
    }
    if constexpr (FOLDED) {   // bias channel: A = 1[exists] at (lq=0, j=0)
      uint4 a4 = make_uint4(0u, 0u, 0u, 0u);
      if (lq == 0 && ok) ((u16*)&a4)[0] = 0x3F80u;
      bf16x8 a = __builtin_bit_cast(bf16x8, a4);
      bf16x8 b0 = __builtin_bit_cast(bf16x8, *(const uint4*)(wb + 8 * 512 + lane * 8));
      bf16x8 b1 = __builtin_bit_cast(bf16x8, *(const uint4*)(wb + 9 * 512 + lane * 8));
      acc0 = __builtin_amdgcn_mfma_f32_32x32x16_bf16(a, b0, acc0, 0, 0, 0);
      acc1 = __builtin_amdgcn_mfma_f32_32x32x16_bf16(a, b1, acc1, 0, 0, 0);
    }
  }

  // Epilogue. C/D (32x32): col = lane&31, row = (reg&3) + 8*(reg>>2) + 4*(lane>>5)
  const int cc0 = lrow, cc1 = 32 + lrow;
  float aD0 = 0.f, aD1 = 0.f, hD0 = 0.f, hD1 = 0.f;
  if constexpr (MODE == 2) {
    aD0 = affD[cc0]; hD0 = affD[64 + cc0];
    aD1 = affD[cc1]; hD1 = affD[64 + cc1];
  }
  float s0 = 0.f, q0 = 0.f, s1 = 0.f, q1 = 0.f;
  float vout[2][16];
#pragma unroll
  for (int r = 0; r < 16; ++r) {
    float v = acc0[r]; v = v > 0.f ? v : 0.01f * v;
    s0 += v; q0 += v * v; vout[0][r] = v;
    float w = acc1[r]; w = w > 0.f ? w : 0.01f * w;
    s1 += w; q1 += w * w; vout[1][r] = w;
  }
  if constexpr (MODE != 2) {   // rows >= NVOX contribute exact 0
    s0 += __shfl_xor(s0, 32); q0 += __shfl_xor(q0, 32);
    s1 += __shfl_xor(s1, 32); q1 += __shfl_xor(q1, 32);
    if (lq == 0) {
      sred[wv][lrow] = s0; sred[wv][32 + lrow] = s1;
      sred[wv][64 + lrow] = q0; sred[wv][96 + lrow] = q1;
    }
  }
  if constexpr (MODE == 0) {
    u16* bb = (u16*)fb;
#pragma unroll
    for (int r = 0; r < 16; ++r) {
      int rowD = 32 * wv + (r & 3) + 8 * (r >> 2) + 4 * lq;
      bb[rowD * 72 + cc0] = f2bf(vout[0][r]);
      bb[rowD * 72 + cc1] = f2bf(vout[1][r]);
    }
  } else if constexpr (MODE == 2 || MODE == 3) {
#pragma unroll
    for (int r = 0; r < 16; ++r) {
      int rowD = 32 * wv + (r & 3) + 8 * (r >> 2) + 4 * lq;
      float v0 = vout[0][r], v1 = vout[1][r];
      if constexpr (MODE == 2) { v0 = fmaf(v0, aD0, hD0); v1 = fmaf(v1, aD1, hD1); }
      fb[rowD * 68 + cc0] = v0;
      fb[rowD * 68 + cc1] = v1;
    }
  }
  __syncthreads();

  const int trow = tid >> 3, cp = tid & 7;
  if constexpr (MODE == 0) {
    u16* y = (u16*)yv;
    const u16* bb = (const u16*)fb;
#pragma unroll
    for (int it = 0; it < 4; ++it) {
      int r = it * 32 + trow, row = base + r;
      if (row < NVOX)
        *(uint4*)(y + (size_t)row * 64 + cp * 8) = *(const uint4*)(bb + r * 72 + cp * 8);
    }
  }
  if constexpr (MODE == 3) {
    float* y = (float*)yv;
#pragma unroll
    for (int it = 0; it < 4; ++it) {
      int r = it * 32 + trow, row = base + r;
      if (row < NVOX) {
        *(float4*)(y + (size_t)row * 64 + cp * 8) = *(const float4*)(fb + r * 68 + cp * 8);
        *(float4*)(y + (size_t)row * 64 + cp * 8 + 4) = *(const float4*)(fb + r * 68 + cp * 8 + 4);
      }
    }
  }
  if constexpr (MODE == 2) {
    float* y = (float*)yv;
#pragma unroll
    for (int it = 0; it < 4; ++it) {
      int r = it * 32 + trow, row = base + r;
      if (row < NVOX) {
        float t[8], p[8], o[8];
        *(float4*)&t[0] = *(const float4*)(fb + r * 68 + cp * 8);
        *(float4*)&t[4] = *(const float4*)(fb + r * 68 + cp * 8 + 4);
        *(float4*)&p[0] = *(const float4*)(io + (size_t)row * 64 + cp * 8);
        *(float4*)&p[4] = *(const float4*)(io + (size_t)row * 64 + cp * 8 + 4);
#pragma unroll
        for (int j = 0; j < 8; ++j) {
          int c = cp * 8 + j;
          o[j] = t[j] + fmaf(p[j], affB[c], affB[64 + c]);
        }
        *(float4*)(y + (size_t)row * 64 + cp * 8) = *(const float4*)&o[0];
        *(float4*)(y + (size_t)row * 64 + cp * 8 + 4) = *(const float4*)&o[4];
      }
    }
  }
  if constexpr (MODE != 2) {
    if (tid < 128) {
      int which = tid >> 6, c = tid & 63;
      float v = sred[0][which * 64 + c] + sred[1][which * 64 + c] +
                sred[2][which * 64 + c] + sred[3][which * 64 + c];
      // replica slot per block: chain length 1563 -> ~49 per address
      atomicAdd(&st[(blockIdx.x & (NREP - 1)) * 128 + which * 64 + c], v);
    }
  }
}

// prep: feat fp32 -> bf16 (big plan), raw weight fragments (w1, w2), zero stats
__global__ void prep_all(const float* __restrict__ feat, const float* __restrict__ w1,
                         const float* __restrict__ w2, u16* __restrict__ wf,
                         u16* __restrict__ F, float* __restrict__ st, int cvt_blocks) {
  const int bid = blockIdx.x, tid = threadIdx.x;
  if (bid < cvt_blocks) {
    int i8 = (bid * 256 + tid) * 8;
    if (i8 < NVOX * 64) {
      uint4 a = *(const uint4*)(feat + i8);
      uint4 b = *(const uint4*)(feat + i8 + 4);
      *(uint4*)(F + i8) = cvt8(a, b);
    }
    return;
  }
  int rb = bid - cvt_blocks;
  if (rb < 288) {   // raw frags: [slot 0|1][k][ks*2+ct][lane][j]
    int e = rb * 256 + tid;
    int slot = e / 36864, r = e % 36864;
    int k = r >> 12, rr = r & 4095;
    int frag = rr >> 9, lane = (rr >> 3) & 63, j = rr & 7;
    int ks = frag >> 1, ct = frag & 1;
    int cin = ks * 16 + (lane >> 5) * 8 + j;
    int cout = ct * 32 + (lane & 31);
    const float* src = slot ? w2 : w1;
    wf[e] = f2bf(src[k * 4096 + cin * 64 + cout]);
    return;
  }
  for (int i = tid; i < 4 * STG; i += 256) st[i] = 0.f;
}

// fold BN(replica-summed stp, g, b) into wraw -> folded frag slot
__global__ void wscale(const float* __restrict__ wraw, float* __restrict__ stp,
                       const float* __restrict__ g, const float* __restrict__ b,
                       u16* __restrict__ dst) {
  __shared__ float sc[64], sh[64];
  const int tid = threadIdx.x;
  if (tid < 64) {
    float s = 0.f, q = 0.f;
#pragma unroll
    for (int r = 0; r < NREP; ++r) {
      s += stp[r * 128 + tid];
      q += stp[r * 128 + 64 + tid];
    }
    const float invn = 1.0f / (float)NVOX;
    float mean = s * invn;
    float var = q * invn - mean * mean;
    float sca = g[tid] * rsqrtf(var + 1e-5f);
    sc[tid] = sca;
    sh[tid] = b[tid] - mean * sca;
    if (blockIdx.x == 0) { stp[4096 + tid] = sca; stp[4160 + tid] = sh[tid]; }
  }
  __syncthreads();
  int e = blockIdx.x * 256 + tid;   // [0, 46080)
  int k = e / 5120, r = e % 5120;
  int frag = r >> 9, lane = (r >> 3) & 63, j = r & 7;
  int ks = frag >> 1, ct = frag & 1;
  int cout = ct * 32 + (lane & 31);
  u16 val = 0;
  if (ks < 4) {
    int cin = ks * 16 + (lane >> 5) * 8 + j;
    val = f2bf(sc[cin] * wraw[k * 4096 + cin * 64 + cout]);
  } else if (((lane >> 5) == 0) && j == 0) {
    float acc = 0.f;
    for (int c = 0; c < 64; ++c) acc += sh[c] * wraw[k * 4096 + c * 64 + cout];
    val = f2bf(acc);
  }
  dst[e] = val;
}

// replica-sum -> st[4096+c]=scale, st[4160+c]=shift
__global__ void finalize_bn(float* __restrict__ st, const float* __restrict__ g,
                            const float* __restrict__ b) {
  int c = threadIdx.x;
  if (c < 64) {
    float s = 0.f, q = 0.f;
#pragma unroll
    for (int r = 0; r < NREP; ++r) {
      s += st[r * 128 + c];
      q += st[r * 128 + 64 + c];
    }
    const float invn = 1.0f / (float)NVOX;
    float mean = s * invn;
    float var = q * invn - mean * mean;
    float sca = g[c] * rsqrtf(var + 1e-5f);
    st[4096 + c] = sca;
    st[4160 + c] = b[c] - mean * sca;
  }
}

// io (fp32, in place) = affB(io) + affD(y3 bf16)
__global__ void final_add(const u16* __restrict__ y3, float* io,
                          const float* __restrict__ affB, const float* __restrict__ affD) {
  int i8 = (blockIdx.x * 256 + threadIdx.x) * 8;
  if (i8 < NVOX * 64) {
    float a[8];
    *(float4*)&a[0] = *(const float4*)(io + i8);
    *(float4*)&a[4] = *(const float4*)(io + i8 + 4);
    uint4 vd = *(const uint4*)(y3 + i8);
    const u16* pd = (const u16*)&vd;
    int cb = i8 & 63;
    float o[8];
#pragma unroll
    for (int j = 0; j < 8; ++j) {
      int c = cb + j;
      o[j] = fmaf(a[j], affB[c], affB[64 + c]) + fmaf(bf2f(pd[j]), affD[c], affD[64 + c]);
    }
    *(float4*)(io + i8) = *(const float4*)&o[0];
    *(float4*)(io + i8 + 4) = *(const float4*)&o[4];
  }
}

extern "C" void kernel_launch(void* const* d_in, const int* in_sizes, int n_in,
                              void* d_out, int out_size, void* d_ws, size_t ws_size,
                              hipStream_t stream) {
  const float* feat = (const float*)d_in[0];
  const float* w1 = (const float*)d_in[1];
  const float* w1_2 = (const float*)d_in[2];
  const float* w2 = (const float*)d_in[3];
  const float* w3 = (const float*)d_in[4];
  const float* g0 = (const float*)d_in[5];
  const float* b0 = (const float*)d_in[6];
  const float* g0_2 = (const float*)d_in[7];
  const float* b0_2 = (const float*)d_in[8];
  const float* g1 = (const float*)d_in[9];
  const float* b1 = (const float*)d_in[10];
  const float* g2 = (const float*)d_in[11];
  const float* b2 = (const float*)d_in[12];
  const int* nbr13 = (const int*)d_in[13];
  const int* nbr31 = (const int*)d_in[14];
  float* out = (float*)d_out;

  char* ws = (char*)d_ws;
  float* st = (float*)ws;                         // 4 stages x 4224 floats = 67,584 B
  u16* wf = (u16*)(ws + 67584);                   // 331,776 B of fragments
  u16* s0 = wf;                                   // w1 raw      (36,864 u16)
  u16* s1 = wf + 36864;                           // w2 raw
  u16* s2 = wf + 73728;                           // w1_2 folded (46,080 u16)
  u16* s3 = wf + 119808;                          // w3 folded
  u16* F = (u16*)(ws + 67584 + 331776);           // feat bf16, 25.6 MB
  u16* A = F + (size_t)NVOX * 64;                 // intermediate, 25.6 MB
  const size_t need_big = 67584 + 331776 + 2ull * NVOX * 64 * 2;
  const bool big = (ws_size >= need_big);

  float* st0 = st, *st1 = st + STG, *st2 = st + 2 * STG, *st3 = st + 3 * STG;

  if (big) {
    prep_all<<<6539, 256, 0, stream>>>(feat, w1, w2, wf, F, st, 6250);
    conv_k<false, false, 0><<<NBLK, 256, 0, stream>>>(F, nbr13, s0, A, st0, nullptr, nullptr, nullptr);
    wscale<<<180, 256, 0, stream>>>(w1_2, st0, g0, b0, s2);
    conv_k<false, true, 3><<<NBLK, 256, 0, stream>>>(A, nbr31, s2, out, st1, nullptr, nullptr, nullptr);
    conv_k<false, false, 0><<<NBLK, 256, 0, stream>>>(F, nbr31, s1, A, st2, nullptr, nullptr, nullptr);
    wscale<<<180, 256, 0, stream>>>(w3, st2, g1, b1, s3);
    conv_k<false, true, 0><<<NBLK, 256, 0, stream>>>(A, nbr13, s3, F, st3, nullptr, nullptr, nullptr);
    finalize_bn<<<1, 64, 0, stream>>>(st1, g0_2, b0_2);
    finalize_bn<<<1, 64, 0, stream>>>(st3, g2, b2);
    final_add<<<6250, 256, 0, stream>>>(F, out, st1 + 4096, st3 + 4096);
  } else {
    u16* Az = F;
    prep_all<<<289, 256, 0, stream>>>(feat, w1, w2, wf, nullptr, st, 0);
    conv_k<true, false, 0><<<NBLK, 256, 0, stream>>>(feat, nbr13, s0, Az, st0, nullptr, nullptr, nullptr);
    wscale<<<180, 256, 0, stream>>>(w1_2, st0, g0, b0, s2);
    conv_k<false, true, 3><<<NBLK, 256, 0, stream>>>(Az, nbr31, s2, out, st1, nullptr, nullptr, nullptr);
    finalize_bn<<<1, 64, 0, stream>>>(st1, g0_2, b0_2);
    conv_k<true, false, 0><<<NBLK, 256, 0, stream>>>(feat, nbr31, s1, Az, st2, nullptr, nullptr, nullptr);
    wscale<<<180, 256, 0, stream>>>(w3, st2, g1, b1, s3);
    conv_k<false, true, 1><<<NBLK, 256, 0, stream>>>(Az, nbr13, s3, nullptr, st3, nullptr, nullptr, nullptr);
    finalize_bn<<<1, 64, 0, stream>>>(st3, g2, b2);
    conv_k<false, true, 2><<<NBLK, 256, 0, stream>>>(Az, nbr13, s3, out, nullptr, out, st3 + 4096, st1 + 4096);
  }
}

// Round 7
// 261.612 us; speedup vs baseline: 1.5698x; 1.0994x over previous
//
#include <hip/hip_runtime.h>

#define NVOX 200000
#define TM 128
#define NBLK 1563   // ceil(200000/128)
#define NREP 64     // stats-accumulator replicas
#define STG 8320    // floats per stage: 64*128 replicas + 64 scale + 64 shift

typedef unsigned short u16;
typedef unsigned int u32;
typedef __bf16 bf16x8 __attribute__((ext_vector_type(8)));
typedef float f32x16 __attribute__((ext_vector_type(16)));

__device__ __forceinline__ float bf2f(u16 h) { return __uint_as_float(((u32)h) << 16); }
__device__ __forceinline__ u16 f2bf(float x) {
  u32 u = __float_as_uint(x);
  u32 r = u + 0x7fffu + ((u >> 16) & 1u);   // RNE
  return (u16)(r >> 16);
}
__device__ __forceinline__ uint4 cvt8(uint4 a, uint4 b) {
  const float* fa = (const float*)&a;
  const float* fb = (const float*)&b;
  uint4 r;
  u16* q = (u16*)&r;
#pragma unroll
  for (int j = 0; j < 4; ++j) { q[j] = f2bf(fa[j]); q[4 + j] = f2bf(fb[j]); }
  return r;
}

// ---------------------------------------------------------------------------
// Fused conv pair: blocks [0,NBLK) run stream A, [NBLK,2*NBLK) stream B.
// K-loop: ballot-skip, register-direct A-fragment gathers, B-frags from L2.
// PHASE 0 (convA): raw weights; both streams -> bf16 + stats.
// PHASE 1 (convB): folded weights (+bias K-step); stream A -> fp32 out + stats,
//                  stream B -> bf16 + stats.
// LDS: 64-row epilogue bounce (~19.5 KB) -> up to 8 blocks/CU.
// ---------------------------------------------------------------------------
template <int PHASE>
__global__ __launch_bounds__(256, 4)
void conv_fused(const u16* __restrict__ inA, const u16* __restrict__ inB,
                const int* __restrict__ nbrA, const int* __restrict__ nbrB,
                const u16* __restrict__ wfA, const u16* __restrict__ wfB,
                void* yA, void* yB, float* __restrict__ stA, float* __restrict__ stB) {
  __shared__ __align__(16) float fb4[64 * 68];   // 17,408 B (u16 alias [64][72])
  __shared__ float sred[4][128];

  const int tid = threadIdx.x;
  const int bid = blockIdx.x;
  const bool hB = (bid >= NBLK);
  const int blk = hB ? bid - NBLK : bid;
  const u16* f = hB ? inB : inA;
  const int* nbr = hB ? nbrB : nbrA;
  const u16* wf = hB ? wfB : wfA;
  float* st = hB ? stB : stA;

  const int wv = tid >> 6;
  const int lane = tid & 63;
  const int lrow = lane & 31;
  const int lq = lane >> 5;
  const int base = blk * TM;
  const int gr = base + wv * 32 + lrow;

  int ids[9];
#pragma unroll
  for (int j = 0; j < 9; ++j) ids[j] = (gr < NVOX) ? nbr[gr * 9 + j] : NVOX;

  f32x16 acc0 = {0.f, 0.f, 0.f, 0.f, 0.f, 0.f, 0.f, 0.f,
                 0.f, 0.f, 0.f, 0.f, 0.f, 0.f, 0.f, 0.f};
  f32x16 acc1 = acc0;
  constexpr bool FOLDED = (PHASE == 1);
  constexpr int KSTRIDE = FOLDED ? 5120 : 4096;

#pragma unroll
  for (int k = 0; k < 9; ++k) {
    if (k != 4) {
      if (__ballot(ids[k] < NVOX) == 0ull) continue;
    }
    const int id = ids[k];
    const bool ok = id < NVOX;
    uint4 af[4];
    const u16* p = f + (size_t)id * 64 + lq * 8;
#pragma unroll
    for (int ksi = 0; ksi < 4; ++ksi) {
      uint4 v = make_uint4(0u, 0u, 0u, 0u);
      if (ok) v = *(const uint4*)(p + ksi * 16);
      af[ksi] = v;
    }
    const u16* wb = wf + k * KSTRIDE;
#pragma unroll
    for (int ksi = 0; ksi < 4; ++ksi) {
      bf16x8 a = __builtin_bit_cast(bf16x8, af[ksi]);
      bf16x8 b0 = __builtin_bit_cast(bf16x8, *(const uint4*)(wb + (ksi * 2) * 512 + lane * 8));
      bf16x8 b1 = __builtin_bit_cast(bf16x8, *(const uint4*)(wb + (ksi * 2 + 1) * 512 + lane * 8));
      acc0 = __builtin_amdgcn_mfma_f32_32x32x16_bf16(a, b0, acc0, 0, 0, 0);
      acc1 = __builtin_amdgcn_mfma_f32_32x32x16_bf16(a, b1, acc1, 0, 0, 0);
    }
    if constexpr (FOLDED) {   // bias channel: A = 1[exists] at (lq=0, j=0)
      uint4 a4 = make_uint4(0u, 0u, 0u, 0u);
      if (lq == 0 && ok) ((u16*)&a4)[0] = 0x3F80u;
      bf16x8 a = __builtin_bit_cast(bf16x8, a4);
      bf16x8 b0 = __builtin_bit_cast(bf16x8, *(const uint4*)(wb + 8 * 512 + lane * 8));
      bf16x8 b1 = __builtin_bit_cast(bf16x8, *(const uint4*)(wb + 9 * 512 + lane * 8));
      acc0 = __builtin_amdgcn_mfma_f32_32x32x16_bf16(a, b0, acc0, 0, 0, 0);
      acc1 = __builtin_amdgcn_mfma_f32_32x32x16_bf16(a, b1, acc1, 0, 0, 0);
    }
  }

  // Epilogue. C/D (32x32): col = lane&31, row = (reg&3) + 8*(reg>>2) + 4*(lane>>5)
  const int cc0 = lrow, cc1 = 32 + lrow;
  float s0 = 0.f, q0 = 0.f, s1 = 0.f, q1 = 0.f;
  float vout[2][16];
#pragma unroll
  for (int r = 0; r < 16; ++r) {
    float v = acc0[r]; v = v > 0.f ? v : 0.01f * v;
    s0 += v; q0 += v * v; vout[0][r] = v;
    float w = acc1[r]; w = w > 0.f ? w : 0.01f * w;
    s1 += w; q1 += w * w; vout[1][r] = w;
  }
  s0 += __shfl_xor(s0, 32); q0 += __shfl_xor(q0, 32);
  s1 += __shfl_xor(s1, 32); q1 += __shfl_xor(q1, 32);
  if (lq == 0) {   // rows >= NVOX contribute exact 0
    sred[wv][lrow] = s0; sred[wv][32 + lrow] = s1;
    sred[wv][64 + lrow] = q0; sred[wv][96 + lrow] = q1;
  }

  const bool f32out = (PHASE == 1) && !hB;
  const int trow = tid >> 3, cp = tid & 7;
  u16* bb = (u16*)fb4;
#pragma unroll
  for (int h = 0; h < 2; ++h) {
    __syncthreads();
    if ((wv >> 1) == h) {
      const int lr = 32 * (wv & 1);
#pragma unroll
      for (int r = 0; r < 16; ++r) {
        int rowD = lr + (r & 3) + 8 * (r >> 2) + 4 * lq;
        if (f32out) {
          fb4[rowD * 68 + cc0] = vout[0][r];
          fb4[rowD * 68 + cc1] = vout[1][r];
        } else {
          bb[rowD * 72 + cc0] = f2bf(vout[0][r]);
          bb[rowD * 72 + cc1] = f2bf(vout[1][r]);
        }
      }
    }
    __syncthreads();
    if (f32out) {
      float* y = (float*)yA;
#pragma unroll
      for (int it = 0; it < 2; ++it) {
        int r = it * 32 + trow, row = base + 64 * h + r;
        if (row < NVOX) {
          *(float4*)(y + (size_t)row * 64 + cp * 8) = *(const float4*)(fb4 + r * 68 + cp * 8);
          *(float4*)(y + (size_t)row * 64 + cp * 8 + 4) = *(const float4*)(fb4 + r * 68 + cp * 8 + 4);
        }
      }
    } else {
      u16* y = (u16*)(hB ? yB : yA);
#pragma unroll
      for (int it = 0; it < 2; ++it) {
        int r = it * 32 + trow, row = base + 64 * h + r;
        if (row < NVOX)
          *(uint4*)(y + (size_t)row * 64 + cp * 8) = *(const uint4*)(bb + r * 72 + cp * 8);
      }
    }
  }
  if (tid < 128) {
    int which = tid >> 6, c = tid & 63;
    float v = sred[0][which * 64 + c] + sred[1][which * 64 + c] +
              sred[2][which * 64 + c] + sred[3][which * 64 + c];
    atomicAdd(&st[(bid & (NREP - 1)) * 128 + which * 64 + c], v);
  }
}

// ---- round-6 serial conv (fallback tiers) ---------------------------------
template <bool IN_F32, bool FOLDED, int MODE>
__global__ __launch_bounds__(256, 4)
void conv_k(const void* __restrict__ fv, const int* __restrict__ nbr,
            const u16* __restrict__ wf, void* yv, float* __restrict__ st,
            float* io, const float* __restrict__ affD,
            const float* __restrict__ affB) {
  __shared__ __align__(16) float fb[128 * 68];
  __shared__ float sred[4][128];

  const int tid = threadIdx.x;
  const int wv = tid >> 6;
  const int lane = tid & 63;
  const int lrow = lane & 31;
  const int lq = lane >> 5;
  const int base = blockIdx.x * TM;
  const int gr = base + wv * 32 + lrow;

  int ids[9];
#pragma unroll
  for (int j = 0; j < 9; ++j) ids[j] = (gr < NVOX) ? nbr[gr * 9 + j] : NVOX;

  f32x16 acc0 = {0.f, 0.f, 0.f, 0.f, 0.f, 0.f, 0.f, 0.f,
                 0.f, 0.f, 0.f, 0.f, 0.f, 0.f, 0.f, 0.f};
  f32x16 acc1 = acc0;
  constexpr int KSTRIDE = FOLDED ? 5120 : 4096;

#pragma unroll
  for (int k = 0; k < 9; ++k) {
    if (k != 4) {
      if (__ballot(ids[k] < NVOX) == 0ull) continue;
    }
    const int id = ids[k];
    const bool ok = id < NVOX;
    uint4 af[4];
    if constexpr (IN_F32) {
      const float* p = (const float*)fv + (size_t)id * 64 + lq * 8;
#pragma unroll
      for (int ksi = 0; ksi < 4; ++ksi) {
        uint4 v0 = make_uint4(0u, 0u, 0u, 0u), v1 = v0;
        if (ok) { v0 = *(const uint4*)(p + ksi * 16); v1 = *(const uint4*)(p + ksi * 16 + 4); }
        af[ksi] = cvt8(v0, v1);
      }
    } else {
      const u16* p = (const u16*)fv + (size_t)id * 64 + lq * 8;
#pragma unroll
      for (int ksi = 0; ksi < 4; ++ksi) {
        uint4 v = make_uint4(0u, 0u, 0u, 0u);
        if (ok) v = *(const uint4*)(p + ksi * 16);
        af[ksi] = v;
      }
    }
    const u16* wb = wf + k * KSTRIDE;
#pragma unroll
    for (int ksi = 0; ksi < 4; ++ksi) {
      bf16x8 a = __builtin_bit_cast(bf16x8, af[ksi]);
      bf16x8 b0 = __builtin_bit_cast(bf16x8, *(const uint4*)(wb + (ksi * 2) * 512 + lane * 8));
      bf16x8 b1 = __builtin_bit_cast(bf16x8, *(const uint4*)(wb + (ksi * 2 + 1) * 512 + lane * 8));
      acc0 = __builtin_amdgcn_mfma_f32_32x32x16_bf16(a, b0, acc0, 0, 0, 0);
      acc1 = __builtin_amdgcn_mfma_f32_32x32x16_bf16(a, b1, acc1, 0, 0, 0);
    }
    if constexpr (FOLDED) {
      uint4 a4 = make_uint4(0u, 0u, 0u, 0u);
      if (lq == 0 && ok) ((u16*)&a4)[0] = 0x3F80u;
      bf16x8 a = __builtin_bit_cast(bf16x8, a4);
      bf16x8 b0 = __builtin_bit_cast(bf16x8, *(const uint4*)(wb + 8 * 512 + lane * 8));
      bf16x8 b1 = __builtin_bit_cast(bf16x8, *(const uint4*)(wb + 9 * 512 + lane * 8));
      acc0 = __builtin_amdgcn_mfma_f32_32x32x16_bf16(a, b0, acc0, 0, 0, 0);
      acc1 = __builtin_amdgcn_mfma_f32_32x32x16_bf16(a, b1, acc1, 0, 0, 0);
    }
  }

  const int cc0 = lrow, cc1 = 32 + lrow;
  float aD0 = 0.f, aD1 = 0.f, hD0 = 0.f, hD1 = 0.f;
  if constexpr (MODE == 2) {
    aD0 = affD[cc0]; hD0 = affD[64 + cc0];
    aD1 = affD[cc1]; hD1 = affD[64 + cc1];
  }
  float s0 = 0.f, q0 = 0.f, s1 = 0.f, q1 = 0.f;
  float vout[2][16];
#pragma unroll
  for (int r = 0; r < 16; ++r) {
    float v = acc0[r]; v = v > 0.f ? v : 0.01f * v;
    s0 += v; q0 += v * v; vout[0][r] = v;
    float w = acc1[r]; w = w > 0.f ? w : 0.01f * w;
    s1 += w; q1 += w * w; vout[1][r] = w;
  }
  if constexpr (MODE != 2) {
    s0 += __shfl_xor(s0, 32); q0 += __shfl_xor(q0, 32);
    s1 += __shfl_xor(s1, 32); q1 += __shfl_xor(q1, 32);
    if (lq == 0) {
      sred[wv][lrow] = s0; sred[wv][32 + lrow] = s1;
      sred[wv][64 + lrow] = q0; sred[wv][96 + lrow] = q1;
    }
  }
  if constexpr (MODE == 0) {
    u16* bb = (u16*)fb;
#pragma unroll
    for (int r = 0; r < 16; ++r) {
      int rowD = 32 * wv + (r & 3) + 8 * (r >> 2) + 4 * lq;
      bb[rowD * 72 + cc0] = f2bf(vout[0][r]);
      bb[rowD * 72 + cc1] = f2bf(vout[1][r]);
    }
  } else if constexpr (MODE == 2 || MODE == 3) {
#pragma unroll
    for (int r = 0; r < 16; ++r) {
      int rowD = 32 * wv + (r & 3) + 8 * (r >> 2) + 4 * lq;
      float v0 = vout[0][r], v1 = vout[1][r];
      if constexpr (MODE == 2) { v0 = fmaf(v0, aD0, hD0); v1 = fmaf(v1, aD1, hD1); }
      fb[rowD * 68 + cc0] = v0;
      fb[rowD * 68 + cc1] = v1;
    }
  }
  __syncthreads();

  const int trow = tid >> 3, cp = tid & 7;
  if constexpr (MODE == 0) {
    u16* y = (u16*)yv;
    const u16* bb = (const u16*)fb;
#pragma unroll
    for (int it = 0; it < 4; ++it) {
      int r = it * 32 + trow, row = base + r;
      if (row < NVOX)
        *(uint4*)(y + (size_t)row * 64 + cp * 8) = *(const uint4*)(bb + r * 72 + cp * 8);
    }
  }
  if constexpr (MODE == 3) {
    float* y = (float*)yv;
#pragma unroll
    for (int it = 0; it < 4; ++it) {
      int r = it * 32 + trow, row = base + r;
      if (row < NVOX) {
        *(float4*)(y + (size_t)row * 64 + cp * 8) = *(const float4*)(fb + r * 68 + cp * 8);
        *(float4*)(y + (size_t)row * 64 + cp * 8 + 4) = *(const float4*)(fb + r * 68 + cp * 8 + 4);
      }
    }
  }
  if constexpr (MODE == 2) {
    float* y = (float*)yv;
#pragma unroll
    for (int it = 0; it < 4; ++it) {
      int r = it * 32 + trow, row = base + r;
      if (row < NVOX) {
        float t[8], p[8], o[8];
        *(float4*)&t[0] = *(const float4*)(fb + r * 68 + cp * 8);
        *(float4*)&t[4] = *(const float4*)(fb + r * 68 + cp * 8 + 4);
        *(float4*)&p[0] = *(const float4*)(io + (size_t)row * 64 + cp * 8);
        *(float4*)&p[4] = *(const float4*)(io + (size_t)row * 64 + cp * 8 + 4);
#pragma unroll
        for (int j = 0; j < 8; ++j) {
          int c = cp * 8 + j;
          o[j] = t[j] + fmaf(p[j], affB[c], affB[64 + c]);
        }
        *(float4*)(y + (size_t)row * 64 + cp * 8) = *(const float4*)&o[0];
        *(float4*)(y + (size_t)row * 64 + cp * 8 + 4) = *(const float4*)&o[4];
      }
    }
  }
  if constexpr (MODE != 2) {
    if (tid < 128) {
      int which = tid >> 6, c = tid & 63;
      float v = sred[0][which * 64 + c] + sred[1][which * 64 + c] +
                sred[2][which * 64 + c] + sred[3][which * 64 + c];
      atomicAdd(&st[(blockIdx.x & (NREP - 1)) * 128 + which * 64 + c], v);
    }
  }
}

// prep: feat fp32 -> bf16, raw weight fragments (w1, w2), zero stats
__global__ void prep_all(const float* __restrict__ feat, const float* __restrict__ w1,
                         const float* __restrict__ w2, u16* __restrict__ wf,
                         u16* __restrict__ F, float* __restrict__ st, int cvt_blocks) {
  const int bid = blockIdx.x, tid = threadIdx.x;
  if (bid < cvt_blocks) {
    int i8 = (bid * 256 + tid) * 8;
    if (i8 < NVOX * 64) {
      uint4 a = *(const uint4*)(feat + i8);
      uint4 b = *(const uint4*)(feat + i8 + 4);
      *(uint4*)(F + i8) = cvt8(a, b);
    }
    return;
  }
  int rb = bid - cvt_blocks;
  if (rb < 288) {   // raw frags: [slot 0|1][k][ks*2+ct][lane][j]
    int e = rb * 256 + tid;
    int slot = e / 36864, r = e % 36864;
    int k = r >> 12, rr = r & 4095;
    int frag = rr >> 9, lane = (rr >> 3) & 63, j = rr & 7;
    int ks = frag >> 1, ct = frag & 1;
    int cin = ks * 16 + (lane >> 5) * 8 + j;
    int cout = ct * 32 + (lane & 31);
    const float* src = slot ? w2 : w1;
    wf[e] = f2bf(src[k * 4096 + cin * 64 + cout]);
    return;
  }
  for (int i = tid; i < 4 * STG; i += 256) st[i] = 0.f;
}

__device__ __forceinline__ void bn_from_replicas(const float* stp, const float* g,
                                                 const float* b, int c,
                                                 float* sc, float* sh) {
  float s = 0.f, q = 0.f;
#pragma unroll
  for (int r = 0; r < NREP; ++r) {
    s += stp[r * 128 + c];
    q += stp[r * 128 + 64 + c];
  }
  const float invn = 1.0f / (float)NVOX;
  float mean = s * invn;
  float var = q * invn - mean * mean;
  float sca = g[c] * rsqrtf(var + 1e-5f);
  *sc = sca;
  *sh = b[c] - mean * sca;
}

// fold both BN stages into both second-conv weights (one dispatch, 360 blocks)
__global__ void wscale2(const float* __restrict__ wA, float* __restrict__ stpA,
                        const float* __restrict__ gA, const float* __restrict__ bA,
                        u16* __restrict__ dA,
                        const float* __restrict__ wB, float* __restrict__ stpB,
                        const float* __restrict__ gB, const float* __restrict__ bB,
                        u16* __restrict__ dB) {
  __shared__ float sc[64], sh[64];
  const int tid = threadIdx.x;
  const bool hB = (blockIdx.x >= 180);
  const float* wraw = hB ? wB : wA;
  float* stp = hB ? stpB : stpA;
  const float* g = hB ? gB : gA;
  const float* b = hB ? bB : bA;
  u16* dst = hB ? dB : dA;
  const int blk = hB ? blockIdx.x - 180 : blockIdx.x;
  if (tid < 64) {
    float a, h;
    bn_from_replicas(stp, g, b, tid, &a, &h);
    sc[tid] = a; sh[tid] = h;
    if (blk == 0) { stp[NREP * 128 + tid] = a; stp[NREP * 128 + 64 + tid] = h; }
  }
  __syncthreads();
  int e = blk * 256 + tid;   // [0, 46080)
  int k = e / 5120, r = e % 5120;
  int frag = r >> 9, lane = (r >> 3) & 63, j = r & 7;
  int ks = frag >> 1, ct = frag & 1;
  int cout = ct * 32 + (lane & 31);
  u16 val = 0;
  if (ks < 4) {
    int cin = ks * 16 + (lane >> 5) * 8 + j;
    val = f2bf(sc[cin] * wraw[k * 4096 + cin * 64 + cout]);
  } else if (((lane >> 5) == 0) && j == 0) {
    float acc = 0.f;
    for (int c = 0; c < 64; ++c) acc += sh[c] * wraw[k * 4096 + c * 64 + cout];
    val = f2bf(acc);
  }
  dst[e] = val;
}

// both output-BN affines in one tiny dispatch
__global__ void finalize2(float* __restrict__ stA, const float* __restrict__ gA,
                          const float* __restrict__ bA, float* __restrict__ stB,
                          const float* __restrict__ gB, const float* __restrict__ bB) {
  int t = threadIdx.x;
  float* stp = (t < 64) ? stA : stB;
  const float* g = (t < 64) ? gA : gB;
  const float* b = (t < 64) ? bA : bB;
  int c = t & 63;
  if (t < 128) {
    float a, h;
    bn_from_replicas(stp, g, b, c, &a, &h);
    stp[NREP * 128 + c] = a;
    stp[NREP * 128 + 64 + c] = h;
  }
}

// io (fp32, in place) = affB(io) + affD(y3 bf16)
__global__ void final_add(const u16* __restrict__ y3, float* io,
                          const float* __restrict__ affB, const float* __restrict__ affD) {
  int i8 = (blockIdx.x * 256 + threadIdx.x) * 8;
  if (i8 < NVOX * 64) {
    float a[8];
    *(float4*)&a[0] = *(const float4*)(io + i8);
    *(float4*)&a[4] = *(const float4*)(io + i8 + 4);
    uint4 vd = *(const uint4*)(y3 + i8);
    const u16* pd = (const u16*)&vd;
    int cb = i8 & 63;
    float o[8];
#pragma unroll
    for (int j = 0; j < 8; ++j) {
      int c = cb + j;
      o[j] = fmaf(a[j], affB[c], affB[64 + c]) + fmaf(bf2f(pd[j]), affD[c], affD[64 + c]);
    }
    *(float4*)(io + i8) = *(const float4*)&o[0];
    *(float4*)(io + i8 + 4) = *(const float4*)&o[4];
  }
}

extern "C" void kernel_launch(void* const* d_in, const int* in_sizes, int n_in,
                              void* d_out, int out_size, void* d_ws, size_t ws_size,
                              hipStream_t stream) {
  const float* feat = (const float*)d_in[0];
  const float* w1 = (const float*)d_in[1];
  const float* w1_2 = (const float*)d_in[2];
  const float* w2 = (const float*)d_in[3];
  const float* w3 = (const float*)d_in[4];
  const float* g0 = (const float*)d_in[5];
  const float* b0 = (const float*)d_in[6];
  const float* g0_2 = (const float*)d_in[7];
  const float* b0_2 = (const float*)d_in[8];
  const float* g1 = (const float*)d_in[9];
  const float* b1 = (const float*)d_in[10];
  const float* g2 = (const float*)d_in[11];
  const float* b2 = (const float*)d_in[12];
  const int* nbr13 = (const int*)d_in[13];
  const int* nbr31 = (const int*)d_in[14];
  float* out = (float*)d_out;

  char* ws = (char*)d_ws;
  float* st = (float*)ws;                         // 4 stages x 8320 f = 133,120 B
  u16* wf = (u16*)(ws + 133120);                  // 331,776 B of fragments
  u16* s0 = wf;                                   // w1 raw      (36,864 u16)
  u16* s1 = wf + 36864;                           // w2 raw
  u16* s2 = wf + 73728;                           // w1_2 folded (46,080 u16)
  u16* s3 = wf + 119808;                          // w3 folded
  u16* F = (u16*)(ws + 133120 + 331776);          // feat bf16 (later Y3), 25.6 MB
  u16* A1 = F + (size_t)NVOX * 64;                // 25.6 MB
  u16* A2 = A1 + (size_t)NVOX * 64;               // 25.6 MB (fused plan only)
  const size_t base_sz = 133120 + 331776;
  const size_t need_fused = base_sz + 3ull * NVOX * 64 * 2;
  const size_t need_serial = base_sz + 2ull * NVOX * 64 * 2;

  float* st0 = st, *st1 = st + STG, *st2 = st + 2 * STG, *st3 = st + 3 * STG;

  if (ws_size >= need_fused) {
    prep_all<<<6539, 256, 0, stream>>>(feat, w1, w2, wf, F, st, 6250);
    // convA: conv1(F,nbr13,s0)->A1,st0  ||  conv2(F,nbr31,s1)->A2,st2
    conv_fused<0><<<2 * NBLK, 256, 0, stream>>>(F, F, nbr13, nbr31, s0, s1,
                                                A1, A2, st0, st2);
    wscale2<<<360, 256, 0, stream>>>(w1_2, st0, g0, b0, s2, w3, st2, g1, b1, s3);
    // convB: conv1_2(A1,nbr31,s2)->out fp32,st1  ||  conv3(A2,nbr13,s3)->F bf16,st3
    conv_fused<1><<<2 * NBLK, 256, 0, stream>>>(A1, A2, nbr31, nbr13, s2, s3,
                                                out, F, st1, st3);
    finalize2<<<1, 128, 0, stream>>>(st1, g0_2, b0_2, st3, g2, b2);
    final_add<<<6250, 256, 0, stream>>>(F, out, st1 + NREP * 128, st3 + NREP * 128);
  } else if (ws_size >= need_serial) {
    prep_all<<<6539, 256, 0, stream>>>(feat, w1, w2, wf, F, st, 6250);
    conv_k<false, false, 0><<<NBLK, 256, 0, stream>>>(F, nbr13, s0, A1, st0, nullptr, nullptr, nullptr);
    wscale2<<<180, 256, 0, stream>>>(w1_2, st0, g0, b0, s2, w3, st2, g1, b1, s3);  // only half used
    conv_k<false, true, 3><<<NBLK, 256, 0, stream>>>(A1, nbr31, s2, out, st1, nullptr, nullptr, nullptr);
    conv_k<false, false, 0><<<NBLK, 256, 0, stream>>>(F, nbr31, s1, A1, st2, nullptr, nullptr, nullptr);
    wscale2<<<360, 256, 0, stream>>>(w1_2, st0, g0, b0, s2, w3, st2, g1, b1, s3);
    conv_k<false, true, 0><<<NBLK, 256, 0, stream>>>(A1, nbr13, s3, F, st3, nullptr, nullptr, nullptr);
    finalize2<<<1, 128, 0, stream>>>(st1, g0_2, b0_2, st3, g2, b2);
    final_add<<<6250, 256, 0, stream>>>(F, out, st1 + NREP * 128, st3 + NREP * 128);
  } else {
    // minimal-ws: recompute path (round-6 small)
    u16* Az = F;
    prep_all<<<289, 256, 0, stream>>>(feat, w1, w2, wf, nullptr, st, 0);
    conv_k<true, false, 0><<<NBLK, 256, 0, stream>>>(feat, nbr13, s0, Az, st0, nullptr, nullptr, nullptr);
    wscale2<<<180, 256, 0, stream>>>(w1_2, st0, g0, b0, s2, w3, st2, g1, b1, s3);
    conv_k<false, true, 3><<<NBLK, 256, 0, stream>>>(Az, nbr31, s2, out, st1, nullptr, nullptr, nullptr);
    finalize2<<<1, 128, 0, stream>>>(st1, g0_2, b0_2, st3, g2, b2);
    conv_k<true, false, 0><<<NBLK, 256, 0, stream>>>(feat, nbr31, s1, Az, st2, nullptr, nullptr, nullptr);
    wscale2<<<360, 256, 0, stream>>>(w1_2, st0, g0, b0, s2, w3, st2, g1, b1, s3);
    conv_k<false, true, 1><<<NBLK, 256, 0, stream>>>(Az, nbr13, s3, nullptr, st3, nullptr, nullptr, nullptr);
    finalize2<<<1, 128, 0, stream>>>(st1, g0_2, b0_2, st3, g2, b2);
    conv_k<false, true, 2><<<NBLK, 256, 0, stream>>>(Az, nbr13, s3, out, nullptr, out,
                                                     st3 + NREP * 128, st1 + NREP * 128);
  }
}